// Round 3
// baseline (704.428 us; speedup 1.0000x reference)
//
#include <hip/hip_runtime.h>

// ---------------------------------------------------------------------------
// AttentionFusion: 3-modality proj(+LN+ReLU) -> 3-token MHA -> gated fusion
// -> classifier.  B=16384, E=512, H=8, HD=64, NC=6.
// R2: latency-tolerance rework of the GEMM — BM=64 (2x grid), double-buffered
// LDS with ONE barrier per k-step, prefetch issued before compute; proj GEMMs
// write bf16 strided into (B,1536) and a single ln3 kernel does all 3 LNs.
// Workspace peak 144,834,560 B (same layout as R1, which ran clean).
// ---------------------------------------------------------------------------

typedef unsigned short u16;
typedef __bf16 bf16x8 __attribute__((ext_vector_type(8)));
typedef float f32x4  __attribute__((ext_vector_type(4)));
typedef unsigned short u16x8 __attribute__((ext_vector_type(8)));
typedef unsigned short u16x4 __attribute__((ext_vector_type(4)));

#define BATCH 16384

__device__ __forceinline__ u16 f2b(float f) {   // RNE f32->bf16
  union { float f; unsigned int u; } c; c.f = f;
  unsigned int u = c.u;
  return (u16)((u + 0x7fffu + ((u >> 16) & 1u)) >> 16);
}
__device__ __forceinline__ float b2f(u16 h) {
  union { unsigned int u; float f; } c; c.u = ((unsigned int)h) << 16;
  return c.f;
}

// ---------------------------------------------------------------------------
// fp32 -> bf16 conversion for the 7 GEMM weight matrices (6.4 MB total)
// ---------------------------------------------------------------------------
struct CvtJobs {
  const float* s[7];
  u16* d[7];
  int n4[7];
};

__global__ __launch_bounds__(256) void cvt_multi(CvtJobs J) {
  const int stride = gridDim.x * blockDim.x;
  const int tid = blockIdx.x * blockDim.x + threadIdx.x;
  for (int ji = 0; ji < 7; ++ji) {
    const f32x4* __restrict__ s = (const f32x4*)J.s[ji];
    u16x4* __restrict__ d = (u16x4*)J.d[ji];
    const int n4 = J.n4[ji];
    for (int i = tid; i < n4; i += stride) {
      f32x4 v = s[i];
      u16x4 o;
      #pragma unroll
      for (int c = 0; c < 4; ++c) o[c] = f2b(v[c]);
      d[i] = o;
    }
  }
}

// ---------------------------------------------------------------------------
// GEMM: C(M,N-slice) = A(M,K) @ B(N,K)^T + bias [+ReLU].
// Tile 64x128, BK=32, 4 waves each 64x32 (4x2 of 16x16x32 MFMA) -> small acc,
// high occupancy.  Double-buffered LDS, ONE __syncthreads per k-step; the
// stage for step s+1 is issued right after the barrier (prefetch head start).
// A is bf16 (ABF=1) or fp32 (ABF=0, converted to bf16 at fragment read).
// EPI: 1=bias 2=bias+relu.  OUTBF: 1=bf16 out, 0=fp32 out.
// C row stride = ldc, column offset = coff (for strided interleaved writes).
// Requires M%64==0, N%128==0, K%32==0.
// ---------------------------------------------------------------------------
template<int ABF, int EPI, int OUTBF>
__global__ __launch_bounds__(256) void gemm64(
    const void* __restrict__ Av, const u16* __restrict__ Bw,
    const float* __restrict__ bias, void* __restrict__ Cv,
    int M, int N, int K, int ldc, int coff)
{
  constexpr int ABYTES  = ABF ? 2 : 4;
  constexpr int ATILE   = 64 * 32 * ABYTES;    // bytes per A stage buffer
  constexpr int AROUNDS = ATILE / 4096;        // 256 lanes x 16B per round
  constexpr int AR_ROWS = ABF ? 64 : 32;       // rows covered per round
  __shared__ __align__(16) char As[2][ATILE];
  __shared__ __align__(16) u16  Bs[2][128 * 32];

  const int t = threadIdx.x;
  const int m0 = blockIdx.y << 6;
  const int n0 = blockIdx.x << 7;
  const int wave = t >> 6, lane = t & 63;
  const int nbase = wave << 5;        // wave's 32-col slice of the 128 cols
  const int lr  = lane & 15;
  const int lk8 = (lane >> 4) << 3;

  // staging coords (16 B per lane per round, row-major contiguous)
  const int arow = ABF ? (t >> 2) : (t >> 3);
  const int acol = ABF ? ((t & 3) << 4) : ((t & 7) << 4);
  const int brow = t >> 2;
  const int bcol = (t & 3) << 4;

  f32x4 acc[4][2] = {};

  const size_t rowBytesA = (size_t)K * ABYTES;
  const size_t rowBytesB = (size_t)K * 2;
  const char* Abase = (const char*)Av + (size_t)m0 * rowBytesA + acol;
  const char* Bbase = (const char*)(Bw + (size_t)n0 * K) + bcol;

  auto stage = [&](int s, int buf) {
    const char* Ak = Abase + (size_t)s * (32 * ABYTES);
    #pragma unroll
    for (int j = 0; j < AROUNDS; ++j)
      __builtin_amdgcn_global_load_lds(
          (const __attribute__((address_space(1))) void*)(Ak + (size_t)(j * AR_ROWS + arow) * rowBytesA),
          (__attribute__((address_space(3))) void*)(&As[buf][(j << 12) + (wave << 10)]),
          16, 0, 0);
    const char* Bk = Bbase + (size_t)s * 64;
    #pragma unroll
    for (int j = 0; j < 2; ++j)
      __builtin_amdgcn_global_load_lds(
          (const __attribute__((address_space(1))) void*)(Bk + (size_t)(j * 64 + brow) * rowBytesB),
          (__attribute__((address_space(3))) void*)((char*)Bs[buf] + (j << 12) + (wave << 10)),
          16, 0, 0);
  };

  const int nsteps = K >> 5;
  stage(0, 0);
  for (int s = 0; s < nsteps; ++s) {
    const int cur = s & 1;
    __syncthreads();                       // drains vmcnt: buf[cur] staged; all
                                           // waves done reading buf[cur^1]
    if (s + 1 < nsteps) stage(s + 1, cur ^ 1);   // prefetch before compute

    bf16x8 af[4], bf[2];
    #pragma unroll
    for (int mi = 0; mi < 4; ++mi) {
      const int r = (mi << 4) + lr;
      if (ABF) {
        af[mi] = __builtin_bit_cast(bf16x8, *(const u16x8*)&((const u16*)As[cur])[r * 32 + lk8]);
      } else {
        const float* Af = (const float*)As[cur];
        f32x4 lo = *(const f32x4*)&Af[r * 32 + lk8];
        f32x4 hi = *(const f32x4*)&Af[r * 32 + lk8 + 4];
        bf16x8 v;
        #pragma unroll
        for (int d = 0; d < 4; ++d) { v[d] = (__bf16)lo[d]; v[4 + d] = (__bf16)hi[d]; }
        af[mi] = v;
      }
    }
    #pragma unroll
    for (int ni = 0; ni < 2; ++ni) {
      const int r = nbase + (ni << 4) + lr;
      bf[ni] = __builtin_bit_cast(bf16x8, *(const u16x8*)&Bs[cur][r * 32 + lk8]);
    }
    #pragma unroll
    for (int mi = 0; mi < 4; ++mi)
      #pragma unroll
      for (int ni = 0; ni < 2; ++ni)
        acc[mi][ni] = __builtin_amdgcn_mfma_f32_16x16x32_bf16(
            af[mi], bf[ni], acc[mi][ni], 0, 0, 0);
  }

  // Epilogue. C/D layout (m89-verified): col = lane&15, row = (lane>>4)*4 + reg
  const int rquad = (lane >> 4) << 2;
  #pragma unroll
  for (int ni = 0; ni < 2; ++ni) {
    const int col = n0 + nbase + (ni << 4) + lr;
    const float bv = bias[col];
    #pragma unroll
    for (int mi = 0; mi < 4; ++mi) {
      const int rowb = m0 + (mi << 4) + rquad;
      #pragma unroll
      for (int r = 0; r < 4; ++r) {
        float v = acc[mi][ni][r] + bv;
        if (EPI == 2) v = fmaxf(v, 0.0f);
        const size_t idx = (size_t)(rowb + r) * ldc + coff + col;
        if (OUTBF) ((u16*)Cv)[idx] = f2b(v);
        else       ((float*)Cv)[idx] = v;
      }
    }
  }
}

// ---------------------------------------------------------------------------
// LN+ReLU over all 3 modality slices of raw (B,1536) bf16 -> rpf (B,1536).
// 384 threads = 6 waves = 2 samples x 3 modalities; one wave per 512-slice.
// ---------------------------------------------------------------------------
__global__ __launch_bounds__(384) void ln3_k(
    const u16* __restrict__ raw, u16* __restrict__ dst,
    const float* __restrict__ g0, const float* __restrict__ b0,
    const float* __restrict__ g1, const float* __restrict__ b1,
    const float* __restrict__ g2, const float* __restrict__ b2)
{
  const int wave = threadIdx.x >> 6, lane = threadIdx.x & 63;
  const int m = wave % 3;
  const int b = blockIdx.x * 2 + wave / 3;
  const size_t off = (size_t)b * 1536 + m * 512 + lane * 8;
  u16x8 xa = *(const u16x8*)&raw[off];
  float x[8];
  float sum = 0.f, sq = 0.f;
  #pragma unroll
  for (int d = 0; d < 8; ++d) { float f = b2f(xa[d]); x[d] = f; sum += f; sq += f * f; }
  #pragma unroll
  for (int o = 32; o > 0; o >>= 1) { sum += __shfl_xor(sum, o); sq += __shfl_xor(sq, o); }
  const float mean = sum * (1.0f / 512.0f);
  const float var = sq * (1.0f / 512.0f) - mean * mean;
  const float rs = rsqrtf(var + 1e-5f);
  const float* g = (m == 0) ? g0 : (m == 1) ? g1 : g2;
  const float* bb = (m == 0) ? b0 : (m == 1) ? b1 : b2;
  u16x8 o;
  #pragma unroll
  for (int d = 0; d < 8; ++d) {
    float y = (x[d] - mean) * rs * g[lane * 8 + d] + bb[lane * 8 + d];
    o[d] = f2b(fmaxf(y, 0.0f));
  }
  *(u16x8*)&dst[off] = o;
}

// ---------------------------------------------------------------------------
// Row LayerNorm + ReLU, bf16 in -> bf16 out. One wave per row, 4 rows/block.
// ---------------------------------------------------------------------------
template<int E>
__global__ __launch_bounds__(256) void ln_relu_k(
    const u16* __restrict__ src, u16* __restrict__ dst,
    const float* __restrict__ gg, const float* __restrict__ bb)
{
  constexpr int V = E >> 6;
  const int wave = threadIdx.x >> 6, lane = threadIdx.x & 63;
  const int row = blockIdx.x * 4 + wave;
  const u16* s = src + (size_t)row * E + lane * V;
  float x[V];
  float sum = 0.f, sq = 0.f;
  #pragma unroll
  for (int i = 0; i < V; i += 4) {
    u16x4 v = *(const u16x4*)(s + i);
    #pragma unroll
    for (int c = 0; c < 4; ++c) { float f = b2f(v[c]); x[i + c] = f; sum += f; sq += f * f; }
  }
  #pragma unroll
  for (int off = 32; off > 0; off >>= 1) {
    sum += __shfl_xor(sum, off);
    sq  += __shfl_xor(sq,  off);
  }
  const float invE = 1.0f / (float)E;
  const float m = sum * invE;
  const float var = sq * invE - m * m;
  const float rs = rsqrtf(var + 1e-5f);
  u16* d = dst + (size_t)row * E + lane * V;
  const float* g = gg + lane * V;
  const float* b = bb + lane * V;
  #pragma unroll
  for (int i = 0; i < V; i += 4) {
    u16x4 o;
    #pragma unroll
    for (int c = 0; c < 4; ++c) {
      float y = (x[i + c] - m) * rs * g[i + c] + b[i + c];
      o[c] = f2b(fmaxf(y, 0.0f));
    }
    *(u16x4*)(d + i) = o;
  }
}

// ---------------------------------------------------------------------------
// 3-token 8-head attention for a chunk of NB samples.
// qkv: (3*NB, 1536) bf16 rows [q|k|v]; ctx: (3*NB, 512) bf16.
// 8 lanes per (b,h), each lane owns 8 of the 64 head dims.
// ---------------------------------------------------------------------------
__global__ __launch_bounds__(256) void attn_k(
    const u16* __restrict__ qkv, u16* __restrict__ ctx)
{
  const int gid = blockIdx.x * 256 + threadIdx.x;
  const int b = gid >> 6;
  const int h = (threadIdx.x >> 3) & 7;
  const int ld = threadIdx.x & 7;
  const size_t rb = (size_t)(3 * b) * 1536 + h * 64 + ld * 8;

  float q[3][8], k[3][8], v[3][8];
  #pragma unroll
  for (int i = 0; i < 3; ++i) {
    u16x8 qa = *(const u16x8*)&qkv[rb + (size_t)i * 1536];
    u16x8 ka = *(const u16x8*)&qkv[rb + (size_t)i * 1536 + 512];
    u16x8 va = *(const u16x8*)&qkv[rb + (size_t)i * 1536 + 1024];
    #pragma unroll
    for (int d = 0; d < 8; ++d) { q[i][d] = b2f(qa[d]); k[i][d] = b2f(ka[d]); v[i][d] = b2f(va[d]); }
  }
  float s[9];
  #pragma unroll
  for (int i = 0; i < 3; ++i)
    #pragma unroll
    for (int j = 0; j < 3; ++j) {
      float a = 0.f;
      #pragma unroll
      for (int d = 0; d < 8; ++d) a += q[i][d] * k[j][d];
      s[i * 3 + j] = a;
    }
  #pragma unroll
  for (int m = 1; m < 8; m <<= 1)
    #pragma unroll
    for (int e = 0; e < 9; ++e) s[e] += __shfl_xor(s[e], m);

  const float sc = 0.125f;  // 1/sqrt(64)
  #pragma unroll
  for (int i = 0; i < 3; ++i) {
    const float a0 = s[i * 3 + 0] * sc, a1 = s[i * 3 + 1] * sc, a2 = s[i * 3 + 2] * sc;
    const float mx = fmaxf(a0, fmaxf(a1, a2));
    float e0 = __expf(a0 - mx), e1 = __expf(a1 - mx), e2 = __expf(a2 - mx);
    const float inv = 1.0f / (e0 + e1 + e2);
    e0 *= inv; e1 *= inv; e2 *= inv;
    u16x8 o;
    #pragma unroll
    for (int d = 0; d < 8; ++d)
      o[d] = f2b(e0 * v[0][d] + e1 * v[1][d] + e2 * v[2][d]);
    *(u16x8*)&ctx[(size_t)(3 * b + i) * 512 + h * 64 + ld * 8] = o;
  }
}

// ---------------------------------------------------------------------------
// gate2 (512->3) + softmax + gate output + weighted sum of attended rows.
// One wave per sample b.
// ---------------------------------------------------------------------------
__global__ __launch_bounds__(256) void gate_fuse_k(
    const u16* __restrict__ gateh, const float* __restrict__ gw2,
    const float* __restrict__ gb2, const u16* __restrict__ att,
    float* __restrict__ gate_out, u16* __restrict__ fused)
{
  const int wave = threadIdx.x >> 6, lane = threadIdx.x & 63;
  const int b = blockIdx.x * 4 + wave;
  float x[8];
  u16x8 xa = *(const u16x8*)&gateh[(size_t)b * 512 + lane * 8];
  #pragma unroll
  for (int d = 0; d < 8; ++d) x[d] = b2f(xa[d]);
  float s[3] = {0.f, 0.f, 0.f};
  #pragma unroll
  for (int j = 0; j < 3; ++j) {
    const float* w = gw2 + j * 512 + lane * 8;
    #pragma unroll
    for (int d = 0; d < 8; ++d) s[j] += x[d] * w[d];
  }
  #pragma unroll
  for (int m = 1; m < 64; m <<= 1)
    #pragma unroll
    for (int j = 0; j < 3; ++j) s[j] += __shfl_xor(s[j], m);
  #pragma unroll
  for (int j = 0; j < 3; ++j) s[j] += gb2[j];
  const float mx = fmaxf(s[0], fmaxf(s[1], s[2]));
  float g0 = __expf(s[0] - mx), g1 = __expf(s[1] - mx), g2 = __expf(s[2] - mx);
  const float inv = 1.0f / (g0 + g1 + g2);
  g0 *= inv; g1 *= inv; g2 *= inv;
  if (lane == 0) { gate_out[b * 3 + 0] = g0; gate_out[b * 3 + 1] = g1; gate_out[b * 3 + 2] = g2; }
  float o[8] = {};
  const float gw[3] = {g0, g1, g2};
  #pragma unroll
  for (int j = 0; j < 3; ++j) {
    u16x8 aa = *(const u16x8*)&att[(size_t)(3 * b + j) * 512 + lane * 8];
    #pragma unroll
    for (int d = 0; d < 8; ++d) o[d] += gw[j] * b2f(aa[d]);
  }
  u16x8 ov;
  #pragma unroll
  for (int d = 0; d < 8; ++d) ov[d] = f2b(o[d]);
  *(u16x8*)&fused[(size_t)b * 512 + lane * 8] = ov;
}

// ---------------------------------------------------------------------------
// classifier tail: logits = h(256) @ cw2(6,256)^T + cb2.  One wave per b.
// ---------------------------------------------------------------------------
__global__ __launch_bounds__(256) void cls2_k(
    const u16* __restrict__ hh, const float* __restrict__ cw2,
    const float* __restrict__ cb2, float* __restrict__ logits)
{
  const int wave = threadIdx.x >> 6, lane = threadIdx.x & 63;
  const int b = blockIdx.x * 4 + wave;
  float x[4];
  u16x4 xa = *(const u16x4*)&hh[(size_t)b * 256 + lane * 4];
  #pragma unroll
  for (int d = 0; d < 4; ++d) x[d] = b2f(xa[d]);
  float s[6] = {};
  #pragma unroll
  for (int j = 0; j < 6; ++j) {
    const float* w = cw2 + j * 256 + lane * 4;
    #pragma unroll
    for (int d = 0; d < 4; ++d) s[j] += x[d] * w[d];
  }
  #pragma unroll
  for (int m = 1; m < 64; m <<= 1)
    #pragma unroll
    for (int j = 0; j < 6; ++j) s[j] += __shfl_xor(s[j], m);
  if (lane < 6) logits[(size_t)b * 6 + lane] = s[lane] + cb2[lane];
}

// ---------------------------------------------------------------------------
extern "C" void kernel_launch(void* const* d_in, const int* in_sizes, int n_in,
                              void* d_out, int out_size, void* d_ws, size_t ws_size,
                              hipStream_t stream) {
  const float* rgb       = (const float*)d_in[0];
  const float* pose      = (const float*)d_in[1];
  const float* flow      = (const float*)d_in[2];
  const float* rgb_w     = (const float*)d_in[3];
  const float* rgb_b     = (const float*)d_in[4];
  const float* rgb_g     = (const float*)d_in[5];
  const float* rgb_beta  = (const float*)d_in[6];
  const float* pose_w    = (const float*)d_in[7];
  const float* pose_b    = (const float*)d_in[8];
  const float* pose_g    = (const float*)d_in[9];
  const float* pose_beta = (const float*)d_in[10];
  const float* flow_w    = (const float*)d_in[11];
  const float* flow_b    = (const float*)d_in[12];
  const float* flow_g    = (const float*)d_in[13];
  const float* flow_beta = (const float*)d_in[14];
  const float* in_w      = (const float*)d_in[15];
  const float* in_b      = (const float*)d_in[16];
  const float* out_w     = (const float*)d_in[17];
  const float* out_b     = (const float*)d_in[18];
  const float* gw1       = (const float*)d_in[19];
  const float* gb1       = (const float*)d_in[20];
  const float* gw2       = (const float*)d_in[21];
  const float* gb2       = (const float*)d_in[22];
  const float* cw1       = (const float*)d_in[23];
  const float* cb1       = (const float*)d_in[24];
  const float* cg        = (const float*)d_in[25];
  const float* cbeta     = (const float*)d_in[26];
  const float* cw2       = (const float*)d_in[27];
  const float* cb2       = (const float*)d_in[28];

  float* logits_out = (float*)d_out;                      // (16384, 6)
  float* gate_out   = (float*)d_out + (size_t)BATCH * 6;  // (16384, 3)

  // ---- static workspace layout, peak 144,834,560 B (~138 MiB) --------------
  // [0, 6.42M)        : 7 weight matrices, bf16
  // rpfB  [6.42M)     : rpf (B,1536) bf16; later att (3B,512) overlays
  // ctxB  [56.75M)    : raw proj (B,1536); then ctx (3B,512); then cls_tmp+h_bf
  // r1B   [107.09M)   : qkv chunk (12288,1536); then gateh (B,512)+fusedb
  char* ws = (char*)d_ws;
  u16* w_rgb  = (u16*)(ws + 0);
  u16* w_pose = (u16*)(ws + 786432);
  u16* w_flow = (u16*)(ws + 1441792);
  u16* w_in   = (u16*)(ws + 2490368);
  u16* w_out  = (u16*)(ws + 4063232);
  u16* w_g1   = (u16*)(ws + 4587520);
  u16* w_c1   = (u16*)(ws + 6160384);
  char* rpfB = ws + 6422528;
  char* ctxB = ws + 56754176;
  char* r1B  = ws + 107085824;

  u16*   rpf      = (u16*)rpfB;     // (B,1536) bf16 — also the (3B,512) view
  u16*   att      = (u16*)rpfB;     // overlay after gate1
  u16*   raw      = (u16*)ctxB;     // (B,1536) bf16 pre-LN proj outputs
  u16*   ctx      = (u16*)ctxB;     // (3B,512) bf16 (raw dead)
  u16*   cls_tmp  = (u16*)ctxB;     // (B,256) bf16 (ctx dead)
  u16*   h_bf     = (u16*)(ctxB + 8388608);
  u16*   qkv_buf  = (u16*)r1B;      // (12288,1536) bf16
  u16*   gateh    = (u16*)r1B;      // (B,512) bf16 (qkv dead)
  u16*   fusedb   = (u16*)(r1B + 16777216); // (B,512) bf16

  // ---- 1. convert GEMM weights to bf16 -------------------------------------
  CvtJobs J;
  const float* srcs[7] = {rgb_w, pose_w, flow_w, in_w, out_w, gw1, cw1};
  u16* dsts[7] = {w_rgb, w_pose, w_flow, w_in, w_out, w_g1, w_c1};
  int ns[7] = {512 * 768, 512 * 640, 512 * 1024, 1536 * 512, 512 * 512, 512 * 1536, 256 * 512};
  for (int i = 0; i < 7; ++i) { J.s[i] = srcs[i]; J.d[i] = dsts[i]; J.n4[i] = ns[i] / 4; }
  cvt_multi<<<512, 256, 0, stream>>>(J);

  dim3 blk(256);
  // ---- 2. proj GEMMs (fp32 A) -> raw (B,1536) strided; one ln3 -> rpf ------
  gemm64<0, 1, 1><<<dim3(4, BATCH / 64), blk, 0, stream>>>(rgb,  w_rgb,  rgb_b,  raw, BATCH, 512, 768,  1536, 0);
  gemm64<0, 1, 1><<<dim3(4, BATCH / 64), blk, 0, stream>>>(pose, w_pose, pose_b, raw, BATCH, 512, 640,  1536, 512);
  gemm64<0, 1, 1><<<dim3(4, BATCH / 64), blk, 0, stream>>>(flow, w_flow, flow_b, raw, BATCH, 512, 1024, 1536, 1024);
  ln3_k<<<BATCH / 2, dim3(384), 0, stream>>>(raw, rpf, rgb_g, rgb_beta, pose_g, pose_beta, flow_g, flow_beta);

  // ---- 3. qkv GEMM + attention, chunked over batch (4 x 4096 samples) ------
  for (int c = 0; c < 4; ++c) {
    const u16* a_chunk = rpf + (size_t)c * 4096 * 1536;
    u16* ctx_chunk = ctx + (size_t)c * 4096 * 3 * 512;
    gemm64<1, 1, 1><<<dim3(12, 3 * 4096 / 64), blk, 0, stream>>>(
        a_chunk, w_in, in_b, qkv_buf, 3 * 4096, 1536, 512, 1536, 0);
    attn_k<<<4096 / 4, blk, 0, stream>>>(qkv_buf, ctx_chunk);
  }

  // ---- 4. gate MLP layer 1 (B x 1536 -> 512) + ReLU (before out-proj so
  //         rpf dies and att can overlay it) ---------------------------------
  gemm64<1, 2, 1><<<dim3(4, BATCH / 64), blk, 0, stream>>>(rpf, w_g1, gb1, gateh, BATCH, 512, 1536, 512, 0);

  // ---- 5. out-proj GEMM (3B x 512 -> 512), att overlays dead rpf -----------
  gemm64<1, 1, 1><<<dim3(4, 3 * BATCH / 64), blk, 0, stream>>>(ctx, w_out, out_b, att, 3 * BATCH, 512, 512, 512, 0);

  // ---- 6. gate2 + softmax + gate output + weighted fuse --------------------
  gate_fuse_k<<<BATCH / 4, blk, 0, stream>>>(gateh, gw2, gb2, att, gate_out, fusedb);

  // ---- 7. classifier: GEMM(+bias) -> LN+ReLU -> logits ---------------------
  gemm64<1, 1, 1><<<dim3(2, BATCH / 64), blk, 0, stream>>>(fusedb, w_c1, cb1, cls_tmp, BATCH, 256, 512, 256, 0);
  ln_relu_k<256><<<BATCH / 4, blk, 0, stream>>>(cls_tmp, h_bf, cg, cbeta);
  cls2_k<<<BATCH / 4, blk, 0, stream>>>(h_bf, cw2, cb2, logits_out);

  (void)in_sizes; (void)n_in; (void)out_size; (void)ws_size;
}

// Round 4
// 585.217 us; speedup vs baseline: 1.2037x; 1.2037x over previous
//
#include <hip/hip_runtime.h>

// ---------------------------------------------------------------------------
// AttentionFusion: 3-modality proj(+LN+ReLU) -> 3-token MHA -> gated fusion
// -> classifier.  B=16384, E=512, H=8, HD=64, NC=6.
// R4: all-bf16 GEMM path. Inputs pre-converted to bf16 (kills fp32-LDS 16-way
// conflicts + HBM refetch). m97-style 128x128 tile, 16 MFMA/wave/step, LDS
// double-buffer with one barrier per k-step. 3 proj GEMMs fused via grid.z.
// Workspace peak 186,777,600 B.
// ---------------------------------------------------------------------------

typedef unsigned short u16;
typedef __bf16 bf16x8 __attribute__((ext_vector_type(8)));
typedef float f32x4  __attribute__((ext_vector_type(4)));
typedef unsigned short u16x8 __attribute__((ext_vector_type(8)));
typedef unsigned short u16x4 __attribute__((ext_vector_type(4)));

#define BATCH 16384

__device__ __forceinline__ u16 f2b(float f) {   // RNE f32->bf16
  union { float f; unsigned int u; } c; c.f = f;
  unsigned int u = c.u;
  return (u16)((u + 0x7fffu + ((u >> 16) & 1u)) >> 16);
}
__device__ __forceinline__ float b2f(u16 h) {
  union { unsigned int u; float f; } c; c.u = ((unsigned int)h) << 16;
  return c.f;
}

// ---------------------------------------------------------------------------
// fp32 -> bf16 conversion: 3 inputs + 7 weight matrices
// ---------------------------------------------------------------------------
struct CvtJobs {
  const float* s[10];
  u16* d[10];
  int n4[10];
};

__global__ __launch_bounds__(256) void cvt_multi(CvtJobs J) {
  const int stride = gridDim.x * blockDim.x;
  const int tid = blockIdx.x * blockDim.x + threadIdx.x;
  for (int ji = 0; ji < 10; ++ji) {
    const f32x4* __restrict__ s = (const f32x4*)J.s[ji];
    u16x4* __restrict__ d = (u16x4*)J.d[ji];
    const int n4 = J.n4[ji];
    for (int i = tid; i < n4; i += stride) {
      f32x4 v = s[i];
      u16x4 o;
      #pragma unroll
      for (int c = 0; c < 4; ++c) o[c] = f2b(v[c]);
      d[i] = o;
    }
  }
}

// ---------------------------------------------------------------------------
// GEMM core: C(128-tile of M x 128-tile of N) = A(M,K) @ B(N,K)^T + bias
// [+ReLU].  All bf16, fp32 acc.  128x128 tile, BK=32, 4 waves each 64x64
// (4x4 of 16x16x32 MFMA).  LDS double-buffered, ONE barrier per k-step,
// prefetch of step s+1 issued right after the barrier.
// C is bf16, row stride ldc, column offset coff.
// ---------------------------------------------------------------------------
template<int EPI>   // 1=bias, 2=bias+relu
__device__ __forceinline__ void gemm_core(
    const u16* __restrict__ A, const u16* __restrict__ Bw,
    const float* __restrict__ bias, u16* __restrict__ C,
    int K, int ldc, int coff, u16* As, u16* Bs)
{
  const int t = threadIdx.x;
  const int m0 = blockIdx.y << 7;
  const int n0 = blockIdx.x << 7;
  const int wave = t >> 6, lane = t & 63;
  const int wm = wave & 1, wn = wave >> 1;
  const int lr  = lane & 15;
  const int lk8 = (lane >> 4) << 3;
  const int srow = t >> 2;            // staging row within 64-row chunk
  const int scol = (t & 3) << 4;      // staging byte col within 64B row

  f32x4 acc[4][4] = {};

  const size_t rowB = (size_t)K * 2;
  const char* Ab = (const char*)A + (size_t)m0 * rowB + scol;
  const char* Bb = (const char*)Bw + (size_t)n0 * rowB + scol;

  auto stage = [&](int s, int buf) {
    const char* Ak = Ab + (size_t)s * 64;
    const char* Bk = Bb + (size_t)s * 64;
    #pragma unroll
    for (int j = 0; j < 2; ++j) {
      __builtin_amdgcn_global_load_lds(
          (const __attribute__((address_space(1))) void*)(Ak + (size_t)(j * 64 + srow) * rowB),
          (__attribute__((address_space(3))) void*)((char*)As + (buf << 13) + (j << 12) + (wave << 10)),
          16, 0, 0);
      __builtin_amdgcn_global_load_lds(
          (const __attribute__((address_space(1))) void*)(Bk + (size_t)(j * 64 + srow) * rowB),
          (__attribute__((address_space(3))) void*)((char*)Bs + (buf << 13) + (j << 12) + (wave << 10)),
          16, 0, 0);
    }
  };

  const int nsteps = K >> 5;
  stage(0, 0);
  for (int s = 0; s < nsteps; ++s) {
    const int cur = s & 1;
    __syncthreads();                         // buf[cur] staged; buf[cur^1] free
    if (s + 1 < nsteps) stage(s + 1, cur ^ 1);   // prefetch before compute

    const u16* Ac = As + (cur << 12);
    const u16* Bc = Bs + (cur << 12);
    bf16x8 af[4], bfr[4];
    #pragma unroll
    for (int mi = 0; mi < 4; ++mi) {
      const int r = (wm << 6) + (mi << 4) + lr;
      af[mi] = __builtin_bit_cast(bf16x8, *(const u16x8*)&Ac[r * 32 + lk8]);
    }
    #pragma unroll
    for (int ni = 0; ni < 4; ++ni) {
      const int r = (wn << 6) + (ni << 4) + lr;
      bfr[ni] = __builtin_bit_cast(bf16x8, *(const u16x8*)&Bc[r * 32 + lk8]);
    }
    #pragma unroll
    for (int mi = 0; mi < 4; ++mi)
      #pragma unroll
      for (int ni = 0; ni < 4; ++ni)
        acc[mi][ni] = __builtin_amdgcn_mfma_f32_16x16x32_bf16(
            af[mi], bfr[ni], acc[mi][ni], 0, 0, 0);
  }

  // Epilogue. C/D layout (m89-verified): col = lane&15, row = (lane>>4)*4 + reg
  const int rquad = (lane >> 4) << 2;
  #pragma unroll
  for (int ni = 0; ni < 4; ++ni) {
    const int col = n0 + (wn << 6) + (ni << 4) + lr;
    const float bv = bias[col];
    #pragma unroll
    for (int mi = 0; mi < 4; ++mi) {
      const int rowb = m0 + (wm << 6) + (mi << 4) + rquad;
      #pragma unroll
      for (int r = 0; r < 4; ++r) {
        float v = acc[mi][ni][r] + bv;
        if (EPI == 2) v = fmaxf(v, 0.0f);
        C[(size_t)(rowb + r) * ldc + coff + col] = f2b(v);
      }
    }
  }
}

template<int EPI>
__global__ __launch_bounds__(256) void gemm128(
    const u16* __restrict__ A, const u16* __restrict__ Bw,
    const float* __restrict__ bias, u16* __restrict__ C,
    int K, int ldc, int coff)
{
  __shared__ __align__(16) u16 As[2][4096];
  __shared__ __align__(16) u16 Bs[2][4096];
  gemm_core<EPI>(A, Bw, bias, C, K, ldc, coff, &As[0][0], &Bs[0][0]);
}

// Fused 3-modality projection: grid.z picks {rgb,pose,flow}; all write into
// the (B,1536) raw buffer at coff {0,512,1024}.
struct P3 {
  const u16* A[3];
  const u16* W[3];
  const float* bias[3];
  int K[3];
  int coff[3];
  u16* C;
};
__global__ __launch_bounds__(256) void proj3_k(P3 p) {
  __shared__ __align__(16) u16 As[2][4096];
  __shared__ __align__(16) u16 Bs[2][4096];
  const int z = blockIdx.z;
  gemm_core<1>(p.A[z], p.W[z], p.bias[z], p.C, p.K[z], 1536, p.coff[z],
               &As[0][0], &Bs[0][0]);
}

// ---------------------------------------------------------------------------
// LN+ReLU over all 3 modality slices of raw (B,1536) bf16 -> rpf (B,1536).
// 384 threads = 6 waves = 2 samples x 3 modalities; one wave per 512-slice.
// ---------------------------------------------------------------------------
__global__ __launch_bounds__(384) void ln3_k(
    const u16* __restrict__ raw, u16* __restrict__ dst,
    const float* __restrict__ g0, const float* __restrict__ b0,
    const float* __restrict__ g1, const float* __restrict__ b1,
    const float* __restrict__ g2, const float* __restrict__ b2)
{
  const int wave = threadIdx.x >> 6, lane = threadIdx.x & 63;
  const int m = wave % 3;
  const int b = blockIdx.x * 2 + wave / 3;
  const size_t off = (size_t)b * 1536 + m * 512 + lane * 8;
  u16x8 xa = *(const u16x8*)&raw[off];
  float x[8];
  float sum = 0.f, sq = 0.f;
  #pragma unroll
  for (int d = 0; d < 8; ++d) { float f = b2f(xa[d]); x[d] = f; sum += f; sq += f * f; }
  #pragma unroll
  for (int o = 32; o > 0; o >>= 1) { sum += __shfl_xor(sum, o); sq += __shfl_xor(sq, o); }
  const float mean = sum * (1.0f / 512.0f);
  const float var = sq * (1.0f / 512.0f) - mean * mean;
  const float rs = rsqrtf(var + 1e-5f);
  const float* g = (m == 0) ? g0 : (m == 1) ? g1 : g2;
  const float* bb = (m == 0) ? b0 : (m == 1) ? b1 : b2;
  u16x8 o;
  #pragma unroll
  for (int d = 0; d < 8; ++d) {
    float y = (x[d] - mean) * rs * g[lane * 8 + d] + bb[lane * 8 + d];
    o[d] = f2b(fmaxf(y, 0.0f));
  }
  *(u16x8*)&dst[off] = o;
}

// ---------------------------------------------------------------------------
// Row LayerNorm + ReLU, bf16 in -> bf16 out. One wave per row, 4 rows/block.
// ---------------------------------------------------------------------------
template<int E>
__global__ __launch_bounds__(256) void ln_relu_k(
    const u16* __restrict__ src, u16* __restrict__ dst,
    const float* __restrict__ gg, const float* __restrict__ bb)
{
  constexpr int V = E >> 6;
  const int wave = threadIdx.x >> 6, lane = threadIdx.x & 63;
  const int row = blockIdx.x * 4 + wave;
  const u16* s = src + (size_t)row * E + lane * V;
  float x[V];
  float sum = 0.f, sq = 0.f;
  #pragma unroll
  for (int i = 0; i < V; i += 4) {
    u16x4 v = *(const u16x4*)(s + i);
    #pragma unroll
    for (int c = 0; c < 4; ++c) { float f = b2f(v[c]); x[i + c] = f; sum += f; sq += f * f; }
  }
  #pragma unroll
  for (int off = 32; off > 0; off >>= 1) {
    sum += __shfl_xor(sum, off);
    sq  += __shfl_xor(sq,  off);
  }
  const float invE = 1.0f / (float)E;
  const float m = sum * invE;
  const float var = sq * invE - m * m;
  const float rs = rsqrtf(var + 1e-5f);
  u16* d = dst + (size_t)row * E + lane * V;
  const float* g = gg + lane * V;
  const float* b = bb + lane * V;
  #pragma unroll
  for (int i = 0; i < V; i += 4) {
    u16x4 o;
    #pragma unroll
    for (int c = 0; c < 4; ++c) {
      float y = (x[i + c] - m) * rs * g[i + c] + b[i + c];
      o[c] = f2b(fmaxf(y, 0.0f));
    }
    *(u16x4*)(d + i) = o;
  }
}

// ---------------------------------------------------------------------------
// 3-token 8-head attention for a chunk of NB samples.
// qkv: (3*NB, 1536) bf16 rows [q|k|v]; ctx: (3*NB, 512) bf16.
// 8 lanes per (b,h), each lane owns 8 of the 64 head dims.
// ---------------------------------------------------------------------------
__global__ __launch_bounds__(256) void attn_k(
    const u16* __restrict__ qkv, u16* __restrict__ ctx)
{
  const int gid = blockIdx.x * 256 + threadIdx.x;
  const int b = gid >> 6;
  const int h = (threadIdx.x >> 3) & 7;
  const int ld = threadIdx.x & 7;
  const size_t rb = (size_t)(3 * b) * 1536 + h * 64 + ld * 8;

  float q[3][8], k[3][8], v[3][8];
  #pragma unroll
  for (int i = 0; i < 3; ++i) {
    u16x8 qa = *(const u16x8*)&qkv[rb + (size_t)i * 1536];
    u16x8 ka = *(const u16x8*)&qkv[rb + (size_t)i * 1536 + 512];
    u16x8 va = *(const u16x8*)&qkv[rb + (size_t)i * 1536 + 1024];
    #pragma unroll
    for (int d = 0; d < 8; ++d) { q[i][d] = b2f(qa[d]); k[i][d] = b2f(ka[d]); v[i][d] = b2f(va[d]); }
  }
  float s[9];
  #pragma unroll
  for (int i = 0; i < 3; ++i)
    #pragma unroll
    for (int j = 0; j < 3; ++j) {
      float a = 0.f;
      #pragma unroll
      for (int d = 0; d < 8; ++d) a += q[i][d] * k[j][d];
      s[i * 3 + j] = a;
    }
  #pragma unroll
  for (int m = 1; m < 8; m <<= 1)
    #pragma unroll
    for (int e = 0; e < 9; ++e) s[e] += __shfl_xor(s[e], m);

  const float sc = 0.125f;  // 1/sqrt(64)
  #pragma unroll
  for (int i = 0; i < 3; ++i) {
    const float a0 = s[i * 3 + 0] * sc, a1 = s[i * 3 + 1] * sc, a2 = s[i * 3 + 2] * sc;
    const float mx = fmaxf(a0, fmaxf(a1, a2));
    float e0 = __expf(a0 - mx), e1 = __expf(a1 - mx), e2 = __expf(a2 - mx);
    const float inv = 1.0f / (e0 + e1 + e2);
    e0 *= inv; e1 *= inv; e2 *= inv;
    u16x8 o;
    #pragma unroll
    for (int d = 0; d < 8; ++d)
      o[d] = f2b(e0 * v[0][d] + e1 * v[1][d] + e2 * v[2][d]);
    *(u16x8*)&ctx[(size_t)(3 * b + i) * 512 + h * 64 + ld * 8] = o;
  }
}

// ---------------------------------------------------------------------------
// gate2 (512->3) + softmax + gate output + weighted sum of attended rows.
// One wave per sample b.
// ---------------------------------------------------------------------------
__global__ __launch_bounds__(256) void gate_fuse_k(
    const u16* __restrict__ gateh, const float* __restrict__ gw2,
    const float* __restrict__ gb2, const u16* __restrict__ att,
    float* __restrict__ gate_out, u16* __restrict__ fused)
{
  const int wave = threadIdx.x >> 6, lane = threadIdx.x & 63;
  const int b = blockIdx.x * 4 + wave;
  float x[8];
  u16x8 xa = *(const u16x8*)&gateh[(size_t)b * 512 + lane * 8];
  #pragma unroll
  for (int d = 0; d < 8; ++d) x[d] = b2f(xa[d]);
  float s[3] = {0.f, 0.f, 0.f};
  #pragma unroll
  for (int j = 0; j < 3; ++j) {
    const float* w = gw2 + j * 512 + lane * 8;
    #pragma unroll
    for (int d = 0; d < 8; ++d) s[j] += x[d] * w[d];
  }
  #pragma unroll
  for (int m = 1; m < 64; m <<= 1)
    #pragma unroll
    for (int j = 0; j < 3; ++j) s[j] += __shfl_xor(s[j], m);
  #pragma unroll
  for (int j = 0; j < 3; ++j) s[j] += gb2[j];
  const float mx = fmaxf(s[0], fmaxf(s[1], s[2]));
  float g0 = __expf(s[0] - mx), g1 = __expf(s[1] - mx), g2 = __expf(s[2] - mx);
  const float inv = 1.0f / (g0 + g1 + g2);
  g0 *= inv; g1 *= inv; g2 *= inv;
  if (lane == 0) { gate_out[b * 3 + 0] = g0; gate_out[b * 3 + 1] = g1; gate_out[b * 3 + 2] = g2; }
  float o[8] = {};
  const float gw[3] = {g0, g1, g2};
  #pragma unroll
  for (int j = 0; j < 3; ++j) {
    u16x8 aa = *(const u16x8*)&att[(size_t)(3 * b + j) * 512 + lane * 8];
    #pragma unroll
    for (int d = 0; d < 8; ++d) o[d] += gw[j] * b2f(aa[d]);
  }
  u16x8 ov;
  #pragma unroll
  for (int d = 0; d < 8; ++d) ov[d] = f2b(o[d]);
  *(u16x8*)&fused[(size_t)b * 512 + lane * 8] = ov;
}

// ---------------------------------------------------------------------------
// classifier tail: logits = h(256) @ cw2(6,256)^T + cb2.  One wave per b.
// ---------------------------------------------------------------------------
__global__ __launch_bounds__(256) void cls2_k(
    const u16* __restrict__ hh, const float* __restrict__ cw2,
    const float* __restrict__ cb2, float* __restrict__ logits)
{
  const int wave = threadIdx.x >> 6, lane = threadIdx.x & 63;
  const int b = blockIdx.x * 4 + wave;
  float x[4];
  u16x4 xa = *(const u16x4*)&hh[(size_t)b * 256 + lane * 4];
  #pragma unroll
  for (int d = 0; d < 4; ++d) x[d] = b2f(xa[d]);
  float s[6] = {};
  #pragma unroll
  for (int j = 0; j < 6; ++j) {
    const float* w = cw2 + j * 256 + lane * 4;
    #pragma unroll
    for (int d = 0; d < 4; ++d) s[j] += x[d] * w[d];
  }
  #pragma unroll
  for (int m = 1; m < 64; m <<= 1)
    #pragma unroll
    for (int j = 0; j < 6; ++j) s[j] += __shfl_xor(s[j], m);
  if (lane < 6) logits[(size_t)b * 6 + lane] = s[lane] + cb2[lane];
}

// ---------------------------------------------------------------------------
extern "C" void kernel_launch(void* const* d_in, const int* in_sizes, int n_in,
                              void* d_out, int out_size, void* d_ws, size_t ws_size,
                              hipStream_t stream) {
  const float* rgb       = (const float*)d_in[0];
  const float* pose      = (const float*)d_in[1];
  const float* flow      = (const float*)d_in[2];
  const float* rgb_w     = (const float*)d_in[3];
  const float* rgb_b     = (const float*)d_in[4];
  const float* rgb_g     = (const float*)d_in[5];
  const float* rgb_beta  = (const float*)d_in[6];
  const float* pose_w    = (const float*)d_in[7];
  const float* pose_b    = (const float*)d_in[8];
  const float* pose_g    = (const float*)d_in[9];
  const float* pose_beta = (const float*)d_in[10];
  const float* flow_w    = (const float*)d_in[11];
  const float* flow_b    = (const float*)d_in[12];
  const float* flow_g    = (const float*)d_in[13];
  const float* flow_beta = (const float*)d_in[14];
  const float* in_w      = (const float*)d_in[15];
  const float* in_b      = (const float*)d_in[16];
  const float* out_w     = (const float*)d_in[17];
  const float* out_b     = (const float*)d_in[18];
  const float* gw1       = (const float*)d_in[19];
  const float* gb1       = (const float*)d_in[20];
  const float* gw2       = (const float*)d_in[21];
  const float* gb2       = (const float*)d_in[22];
  const float* cw1       = (const float*)d_in[23];
  const float* cb1       = (const float*)d_in[24];
  const float* cg        = (const float*)d_in[25];
  const float* cbeta     = (const float*)d_in[26];
  const float* cw2       = (const float*)d_in[27];
  const float* cb2       = (const float*)d_in[28];

  float* logits_out = (float*)d_out;                      // (16384, 6)
  float* gate_out   = (float*)d_out + (size_t)BATCH * 6;  // (16384, 3)

  // ---- static workspace layout, peak 186,777,600 B -------------------------
  // [0, 6.42M)      : 7 weight matrices, bf16
  // rpfB [6.42M)    : rpf (B,1536) bf16; att (3B,512) overlays after gate1
  // ctxB [56.75M)   : raw (B,1536); then ctx (3B,512); then cls_tmp + h_bf
  // r1B  [107.09M)  : bf16 inputs (79.7M, dead after proj) -> qkv chunks
  //                   (75.5M) -> gateh (16.8M) + fusedb
  char* ws = (char*)d_ws;
  u16* w_rgb  = (u16*)(ws + 0);
  u16* w_pose = (u16*)(ws + 786432);
  u16* w_flow = (u16*)(ws + 1441792);
  u16* w_in   = (u16*)(ws + 2490368);
  u16* w_out  = (u16*)(ws + 4063232);
  u16* w_g1   = (u16*)(ws + 4587520);
  u16* w_c1   = (u16*)(ws + 6160384);
  char* rpfB = ws + 6422528;
  char* ctxB = ws + 56754176;
  char* r1B  = ws + 107085824;

  u16*   rpf      = (u16*)rpfB;     // (B,1536) bf16 — also the (3B,512) view
  u16*   att      = (u16*)rpfB;     // overlay after gate1
  u16*   raw      = (u16*)ctxB;     // (B,1536) bf16 pre-LN proj outputs
  u16*   ctx      = (u16*)ctxB;     // (3B,512) bf16 (raw dead)
  u16*   cls_tmp  = (u16*)ctxB;     // (B,256) bf16 (ctx dead)
  u16*   h_bf     = (u16*)(ctxB + 8388608);
  u16*   rgb_bf   = (u16*)r1B;                    // 25.2M
  u16*   pose_bf  = (u16*)(r1B + 25165824);       // 21.0M
  u16*   flow_bf  = (u16*)(r1B + 46137344);       // 33.6M -> ends 186.78M
  u16*   qkv_buf  = (u16*)r1B;      // (24576,1536) bf16 chunk (75.5M), inputs dead
  u16*   gateh    = (u16*)r1B;      // (B,512) bf16 (qkv dead)
  u16*   fusedb   = (u16*)(r1B + 16777216);

  // ---- 1. convert inputs + GEMM weights to bf16 ----------------------------
  CvtJobs J;
  const float* srcs[10] = {rgb, pose, flow, rgb_w, pose_w, flow_w, in_w, out_w, gw1, cw1};
  u16* dsts[10] = {rgb_bf, pose_bf, flow_bf, w_rgb, w_pose, w_flow, w_in, w_out, w_g1, w_c1};
  int ns[10] = {BATCH * 768, BATCH * 640, BATCH * 1024, 512 * 768, 512 * 640,
                512 * 1024, 1536 * 512, 512 * 512, 512 * 1536, 256 * 512};
  for (int i = 0; i < 10; ++i) { J.s[i] = srcs[i]; J.d[i] = dsts[i]; J.n4[i] = ns[i] / 4; }
  cvt_multi<<<2048, 256, 0, stream>>>(J);

  dim3 blk(256);
  // ---- 2. fused 3-proj GEMM -> raw (B,1536); one ln3 -> rpf ----------------
  P3 p;
  p.A[0] = rgb_bf;  p.W[0] = w_rgb;  p.bias[0] = rgb_b;  p.K[0] = 768;  p.coff[0] = 0;
  p.A[1] = pose_bf; p.W[1] = w_pose; p.bias[1] = pose_b; p.K[1] = 640;  p.coff[1] = 512;
  p.A[2] = flow_bf; p.W[2] = w_flow; p.bias[2] = flow_b; p.K[2] = 1024; p.coff[2] = 1024;
  p.C = raw;
  proj3_k<<<dim3(4, BATCH / 128, 3), blk, 0, stream>>>(p);
  ln3_k<<<BATCH / 2, dim3(384), 0, stream>>>(raw, rpf, rgb_g, rgb_beta, pose_g, pose_beta, flow_g, flow_beta);

  // ---- 3. qkv GEMM + attention, 2 chunks of 8192 samples -------------------
  for (int c = 0; c < 2; ++c) {
    const u16* a_chunk = rpf + (size_t)c * 8192 * 1536;   // (24576,512) view
    u16* ctx_chunk = ctx + (size_t)c * 8192 * 3 * 512;
    gemm128<1><<<dim3(12, 3 * 8192 / 128), blk, 0, stream>>>(
        a_chunk, w_in, in_b, qkv_buf, 512, 1536, 0);
    attn_k<<<8192 / 4, blk, 0, stream>>>(qkv_buf, ctx_chunk);
  }

  // ---- 4. gate MLP layer 1 (B x 1536 -> 512) + ReLU (before out-proj so
  //         rpf dies and att can overlay it) ---------------------------------
  gemm128<2><<<dim3(4, BATCH / 128), blk, 0, stream>>>(rpf, w_g1, gb1, gateh, 1536, 512, 0);

  // ---- 5. out-proj GEMM (3B x 512 -> 512), att overlays dead rpf -----------
  gemm128<1><<<dim3(4, 3 * BATCH / 128), blk, 0, stream>>>(ctx, w_out, out_b, att, 512, 512, 0);

  // ---- 6. gate2 + softmax + gate output + weighted fuse --------------------
  gate_fuse_k<<<BATCH / 4, blk, 0, stream>>>(gateh, gw2, gb2, att, gate_out, fusedb);

  // ---- 7. classifier: GEMM(+bias) -> LN+ReLU -> logits ---------------------
  gemm128<1><<<dim3(2, BATCH / 128), blk, 0, stream>>>(fusedb, w_c1, cb1, cls_tmp, 512, 256, 0);
  ln_relu_k<256><<<BATCH / 4, blk, 0, stream>>>(cls_tmp, h_bf, cg, cbeta);
  cls2_k<<<BATCH / 4, blk, 0, stream>>>(h_bf, cw2, cb2, logits_out);

  (void)in_sizes; (void)n_in; (void)out_size; (void)ws_size;
}

// Round 5
// 574.495 us; speedup vs baseline: 1.2262x; 1.0187x over previous
//
#include <hip/hip_runtime.h>

// ---------------------------------------------------------------------------
// AttentionFusion: 3-modality proj(+LN+ReLU) -> 3-token MHA -> gated fusion
// -> classifier.  B=16384, E=512, H=8, HD=64, NC=6.
// R5: (a) gate computed BEFORE attention; attention emits the gated sum
//     directly (exact by softmax-sum=1 linearity) -> out-proj is (B,512)
//     not (3B,512), att/gate_fuse passes gone.
// (b) proj GEMM reads fp32 inputs directly (reg-stage + in-reg bf16 cvt +
//     ds_write), eliminating the 320 MB input-conversion pass. LDS stays bf16.
// GEMM core: 128x128 bf16 MFMA 16x16x32, LDS dbuf, one barrier/k-step.
// Workspace peak 165,806,080 B (< R4's 186.8 MB which ran clean).
// ---------------------------------------------------------------------------

typedef unsigned short u16;
typedef __bf16 bf16x8 __attribute__((ext_vector_type(8)));
typedef float f32x4  __attribute__((ext_vector_type(4)));
typedef unsigned short u16x8 __attribute__((ext_vector_type(8)));
typedef unsigned short u16x4 __attribute__((ext_vector_type(4)));

#define BATCH 16384

__device__ __forceinline__ u16 f2b(float f) {   // RNE f32->bf16
  union { float f; unsigned int u; } c; c.f = f;
  unsigned int u = c.u;
  return (u16)((u + 0x7fffu + ((u >> 16) & 1u)) >> 16);
}
__device__ __forceinline__ float b2f(u16 h) {
  union { unsigned int u; float f; } c; c.u = ((unsigned int)h) << 16;
  return c.f;
}

// ---------------------------------------------------------------------------
// fp32 -> bf16 conversion for the 7 GEMM weight matrices (6.4 MB total)
// ---------------------------------------------------------------------------
struct CvtJobs {
  const float* s[7];
  u16* d[7];
  int n4[7];
};

__global__ __launch_bounds__(256) void cvt_w(CvtJobs J) {
  const int stride = gridDim.x * blockDim.x;
  const int tid = blockIdx.x * blockDim.x + threadIdx.x;
  for (int ji = 0; ji < 7; ++ji) {
    const f32x4* __restrict__ s = (const f32x4*)J.s[ji];
    u16x4* __restrict__ d = (u16x4*)J.d[ji];
    const int n4 = J.n4[ji];
    for (int i = tid; i < n4; i += stride) {
      f32x4 v = s[i];
      u16x4 o;
      #pragma unroll
      for (int c = 0; c < 4; ++c) o[c] = f2b(v[c]);
      d[i] = o;
    }
  }
}

// ---------------------------------------------------------------------------
// bf16 GEMM: C(M,N) = A(M,K) @ B(N,K)^T + bias [+ReLU].  128x128 tile, BK=32,
// 4 waves each 64x64 (4x4 of 16x16x32 MFMA).  LDS double-buffered, ONE
// barrier per k-step, prefetch issued right after the barrier.
// ---------------------------------------------------------------------------
template<int EPI>   // 1=bias, 2=bias+relu
__global__ __launch_bounds__(256) void gemm128(
    const u16* __restrict__ A, const u16* __restrict__ Bw,
    const float* __restrict__ bias, u16* __restrict__ C,
    int K, int ldc, int coff)
{
  __shared__ __align__(16) u16 As[2][4096];
  __shared__ __align__(16) u16 Bs[2][4096];
  const int t = threadIdx.x;
  const int m0 = blockIdx.y << 7;
  const int n0 = blockIdx.x << 7;
  const int wave = t >> 6, lane = t & 63;
  const int wm = wave & 1, wn = wave >> 1;
  const int lr  = lane & 15;
  const int lk8 = (lane >> 4) << 3;
  const int srow = t >> 2;
  const int scol = (t & 3) << 4;

  f32x4 acc[4][4] = {};

  const size_t rowB = (size_t)K * 2;
  const char* Ab = (const char*)A + (size_t)m0 * rowB + scol;
  const char* Bb = (const char*)Bw + (size_t)n0 * rowB + scol;

  auto stage = [&](int s, int buf) {
    const char* Ak = Ab + (size_t)s * 64;
    const char* Bk = Bb + (size_t)s * 64;
    #pragma unroll
    for (int j = 0; j < 2; ++j) {
      __builtin_amdgcn_global_load_lds(
          (const __attribute__((address_space(1))) void*)(Ak + (size_t)(j * 64 + srow) * rowB),
          (__attribute__((address_space(3))) void*)((char*)As[buf] + (j << 12) + (wave << 10)),
          16, 0, 0);
      __builtin_amdgcn_global_load_lds(
          (const __attribute__((address_space(1))) void*)(Bk + (size_t)(j * 64 + srow) * rowB),
          (__attribute__((address_space(3))) void*)((char*)Bs[buf] + (j << 12) + (wave << 10)),
          16, 0, 0);
    }
  };

  const int nsteps = K >> 5;
  stage(0, 0);
  for (int s = 0; s < nsteps; ++s) {
    const int cur = s & 1;
    __syncthreads();
    if (s + 1 < nsteps) stage(s + 1, cur ^ 1);

    bf16x8 af[4], bfr[4];
    #pragma unroll
    for (int mi = 0; mi < 4; ++mi) {
      const int r = (wm << 6) + (mi << 4) + lr;
      af[mi] = __builtin_bit_cast(bf16x8, *(const u16x8*)&As[cur][r * 32 + lk8]);
    }
    #pragma unroll
    for (int ni = 0; ni < 4; ++ni) {
      const int r = (wn << 6) + (ni << 4) + lr;
      bfr[ni] = __builtin_bit_cast(bf16x8, *(const u16x8*)&Bs[cur][r * 32 + lk8]);
    }
    #pragma unroll
    for (int mi = 0; mi < 4; ++mi)
      #pragma unroll
      for (int ni = 0; ni < 4; ++ni)
        acc[mi][ni] = __builtin_amdgcn_mfma_f32_16x16x32_bf16(
            af[mi], bfr[ni], acc[mi][ni], 0, 0, 0);
  }

  // C/D layout (m89-verified): col = lane&15, row = (lane>>4)*4 + reg
  const int rquad = (lane >> 4) << 2;
  #pragma unroll
  for (int ni = 0; ni < 4; ++ni) {
    const int col = n0 + (wn << 6) + (ni << 4) + lr;
    const float bv = bias[col];
    #pragma unroll
    for (int mi = 0; mi < 4; ++mi) {
      const int rowb = m0 + (wm << 6) + (mi << 4) + rquad;
      #pragma unroll
      for (int r = 0; r < 4; ++r) {
        float v = acc[mi][ni][r] + bv;
        if (EPI == 2) v = fmaxf(v, 0.0f);
        C[(size_t)(rowb + r) * ldc + coff + col] = f2b(v);
      }
    }
  }
}

// ---------------------------------------------------------------------------
// Fused 3-modality projection GEMM, fp32 A read directly from the inputs.
// A path: per-lane global f32x4 loads -> in-register bf16 cvt -> ds_write_b64
// (LDS holds bf16; MFMA inner loop identical to gemm128). B via
// global_load_lds. grid.z = modality; C = raw (B,1536) at coff {0,512,1024}.
// ---------------------------------------------------------------------------
struct P3 {
  const float* A[3];
  const u16* W[3];
  const float* bias[3];
  int K[3];
  int coff[3];
  u16* C;
};

__global__ __launch_bounds__(256) void proj3_k(P3 p) {
  __shared__ __align__(16) u16 As[2][4096];
  __shared__ __align__(16) u16 Bs[2][4096];
  const int z = blockIdx.z;
  const float* __restrict__ A = p.A[z];
  const u16* __restrict__ Bw = p.W[z];
  const int K = p.K[z];

  const int t = threadIdx.x;
  const int m0 = blockIdx.y << 7;
  const int n0 = blockIdx.x << 7;
  const int wave = t >> 6, lane = t & 63;
  const int wm = wave & 1, wn = wave >> 1;
  const int lr  = lane & 15;
  const int lk8 = (lane >> 4) << 3;
  // A reg-staging: round j covers rows j*32+(t>>3); cols (t&7)*4..+3 (fp32)
  const int ar = t >> 3;
  const int ac = (t & 7) << 2;
  // B staging via global_load_lds
  const int srow = t >> 2;
  const int scol = (t & 3) << 4;

  f32x4 acc[4][4] = {};

  const size_t rowA = (size_t)K;        // floats
  const size_t rowB = (size_t)K * 2;    // bytes
  const float* Abase = A + (size_t)m0 * rowA + ac;
  const char* Bb = (const char*)Bw + (size_t)n0 * rowB + scol;

  f32x4 areg[4];
  auto loadA = [&](int s) {
    const float* Ak = Abase + s * 32;
    #pragma unroll
    for (int j = 0; j < 4; ++j)
      areg[j] = *(const f32x4*)(Ak + (size_t)(j * 32 + ar) * rowA);
  };
  auto writeA = [&](int buf) {
    #pragma unroll
    for (int j = 0; j < 4; ++j) {
      u16x4 o;
      #pragma unroll
      for (int c = 0; c < 4; ++c) o[c] = f2b(areg[j][c]);
      *(u16x4*)&As[buf][(j * 32 + ar) * 32 + ac] = o;
    }
  };
  auto stageB = [&](int s, int buf) {
    const char* Bk = Bb + (size_t)s * 64;
    #pragma unroll
    for (int j = 0; j < 2; ++j)
      __builtin_amdgcn_global_load_lds(
          (const __attribute__((address_space(1))) void*)(Bk + (size_t)(j * 64 + srow) * rowB),
          (__attribute__((address_space(3))) void*)((char*)Bs[buf] + (j << 12) + (wave << 10)),
          16, 0, 0);
  };

  const int nsteps = K >> 5;
  loadA(0);
  stageB(0, 0);
  writeA(0);
  for (int s = 0; s < nsteps; ++s) {
    const int cur = s & 1;
    __syncthreads();                       // publishes buf[cur]
    if (s + 1 < nsteps) { loadA(s + 1); stageB(s + 1, cur ^ 1); }

    bf16x8 af[4], bfr[4];
    #pragma unroll
    for (int mi = 0; mi < 4; ++mi) {
      const int r = (wm << 6) + (mi << 4) + lr;
      af[mi] = __builtin_bit_cast(bf16x8, *(const u16x8*)&As[cur][r * 32 + lk8]);
    }
    #pragma unroll
    for (int ni = 0; ni < 4; ++ni) {
      const int r = (wn << 6) + (ni << 4) + lr;
      bfr[ni] = __builtin_bit_cast(bf16x8, *(const u16x8*)&Bs[cur][r * 32 + lk8]);
    }
    #pragma unroll
    for (int mi = 0; mi < 4; ++mi)
      #pragma unroll
      for (int ni = 0; ni < 4; ++ni)
        acc[mi][ni] = __builtin_amdgcn_mfma_f32_16x16x32_bf16(
            af[mi], bfr[ni], acc[mi][ni], 0, 0, 0);

    if (s + 1 < nsteps) writeA(cur ^ 1);   // cvt + LDS write for next step
  }

  const int rquad = (lane >> 4) << 2;
  #pragma unroll
  for (int ni = 0; ni < 4; ++ni) {
    const int col = n0 + (wn << 6) + (ni << 4) + lr;
    const float bv = p.bias[z][col];
    #pragma unroll
    for (int mi = 0; mi < 4; ++mi) {
      const int rowb = m0 + (wm << 6) + (mi << 4) + rquad;
      #pragma unroll
      for (int r = 0; r < 4; ++r) {
        p.C[(size_t)(rowb + r) * 1536 + p.coff[z] + col] = f2b(acc[mi][ni][r] + bv);
      }
    }
  }
}

// ---------------------------------------------------------------------------
// LN+ReLU over all 3 modality slices of raw (B,1536) bf16 -> rpf (B,1536).
// 384 threads = 6 waves = 2 samples x 3 modalities; one wave per 512-slice.
// ---------------------------------------------------------------------------
__global__ __launch_bounds__(384) void ln3_k(
    const u16* __restrict__ raw, u16* __restrict__ dst,
    const float* __restrict__ g0, const float* __restrict__ b0,
    const float* __restrict__ g1, const float* __restrict__ b1,
    const float* __restrict__ g2, const float* __restrict__ b2)
{
  const int wave = threadIdx.x >> 6, lane = threadIdx.x & 63;
  const int m = wave % 3;
  const int b = blockIdx.x * 2 + wave / 3;
  const size_t off = (size_t)b * 1536 + m * 512 + lane * 8;
  u16x8 xa = *(const u16x8*)&raw[off];
  float x[8];
  float sum = 0.f, sq = 0.f;
  #pragma unroll
  for (int d = 0; d < 8; ++d) { float f = b2f(xa[d]); x[d] = f; sum += f; sq += f * f; }
  #pragma unroll
  for (int o = 32; o > 0; o >>= 1) { sum += __shfl_xor(sum, o); sq += __shfl_xor(sq, o); }
  const float mean = sum * (1.0f / 512.0f);
  const float var = sq * (1.0f / 512.0f) - mean * mean;
  const float rs = rsqrtf(var + 1e-5f);
  const float* g = (m == 0) ? g0 : (m == 1) ? g1 : g2;
  const float* bb = (m == 0) ? b0 : (m == 1) ? b1 : b2;
  u16x8 o;
  #pragma unroll
  for (int d = 0; d < 8; ++d) {
    float y = (x[d] - mean) * rs * g[lane * 8 + d] + bb[lane * 8 + d];
    o[d] = f2b(fmaxf(y, 0.0f));
  }
  *(u16x8*)&dst[off] = o;
}

// ---------------------------------------------------------------------------
// Row LayerNorm + ReLU, bf16 in -> bf16 out. One wave per row, 4 rows/block.
// ---------------------------------------------------------------------------
template<int E>
__global__ __launch_bounds__(256) void ln_relu_k(
    const u16* __restrict__ src, u16* __restrict__ dst,
    const float* __restrict__ gg, const float* __restrict__ bb)
{
  constexpr int V = E >> 6;
  const int wave = threadIdx.x >> 6, lane = threadIdx.x & 63;
  const int row = blockIdx.x * 4 + wave;
  const u16* s = src + (size_t)row * E + lane * V;
  float x[V];
  float sum = 0.f, sq = 0.f;
  #pragma unroll
  for (int i = 0; i < V; i += 4) {
    u16x4 v = *(const u16x4*)(s + i);
    #pragma unroll
    for (int c = 0; c < 4; ++c) { float f = b2f(v[c]); x[i + c] = f; sum += f; sq += f * f; }
  }
  #pragma unroll
  for (int off = 32; off > 0; off >>= 1) {
    sum += __shfl_xor(sum, off);
    sq  += __shfl_xor(sq,  off);
  }
  const float invE = 1.0f / (float)E;
  const float m = sum * invE;
  const float var = sq * invE - m * m;
  const float rs = rsqrtf(var + 1e-5f);
  u16* d = dst + (size_t)row * E + lane * V;
  const float* g = gg + lane * V;
  const float* b = bb + lane * V;
  #pragma unroll
  for (int i = 0; i < V; i += 4) {
    u16x4 o;
    #pragma unroll
    for (int c = 0; c < 4; ++c) {
      float y = (x[i + c] - m) * rs * g[i + c] + b[i + c];
      o[c] = f2b(fmaxf(y, 0.0f));
    }
    *(u16x4*)(d + i) = o;
  }
}

// ---------------------------------------------------------------------------
// gate2: (512->3) + softmax.  One wave per sample; writes gate_out (B,3) fp32.
// ---------------------------------------------------------------------------
__global__ __launch_bounds__(256) void gate2_k(
    const u16* __restrict__ gateh, const float* __restrict__ gw2,
    const float* __restrict__ gb2, float* __restrict__ gate_out)
{
  const int wave = threadIdx.x >> 6, lane = threadIdx.x & 63;
  const int b = blockIdx.x * 4 + wave;
  float x[8];
  u16x8 xa = *(const u16x8*)&gateh[(size_t)b * 512 + lane * 8];
  #pragma unroll
  for (int d = 0; d < 8; ++d) x[d] = b2f(xa[d]);
  float s[3] = {0.f, 0.f, 0.f};
  #pragma unroll
  for (int j = 0; j < 3; ++j) {
    const float* w = gw2 + j * 512 + lane * 8;
    #pragma unroll
    for (int d = 0; d < 8; ++d) s[j] += x[d] * w[d];
  }
  #pragma unroll
  for (int m = 1; m < 64; m <<= 1)
    #pragma unroll
    for (int j = 0; j < 3; ++j) s[j] += __shfl_xor(s[j], m);
  if (lane == 0) {
    #pragma unroll
    for (int j = 0; j < 3; ++j) s[j] += gb2[j];
    const float mx = fmaxf(s[0], fmaxf(s[1], s[2]));
    float e0 = __expf(s[0] - mx), e1 = __expf(s[1] - mx), e2 = __expf(s[2] - mx);
    const float inv = 1.0f / (e0 + e1 + e2);
    gate_out[b * 3 + 0] = e0 * inv;
    gate_out[b * 3 + 1] = e1 * inv;
    gate_out[b * 3 + 2] = e2 * inv;
  }
}

// ---------------------------------------------------------------------------
// 3-token 8-head attention + gate application for a chunk of NB samples.
// qkv: (3*NB,1536) bf16 [q|k|v]; emits the GATED context sum directly:
// ctxg[b0+b] = sum_i gate_i * ctx_i   (exact: out-proj is linear, sum g = 1).
// 8 lanes per (b,h), each lane owns 8 of the 64 head dims.
// ---------------------------------------------------------------------------
__global__ __launch_bounds__(256) void attn_gate_k(
    const u16* __restrict__ qkv, const float* __restrict__ gate,
    u16* __restrict__ ctxg, int b0)
{
  const int gid = blockIdx.x * 256 + threadIdx.x;
  const int b = gid >> 6;
  const int h = (threadIdx.x >> 3) & 7;
  const int ld = threadIdx.x & 7;
  const size_t rb = (size_t)(3 * b) * 1536 + h * 64 + ld * 8;

  float q[3][8], k[3][8], v[3][8];
  #pragma unroll
  for (int i = 0; i < 3; ++i) {
    u16x8 qa = *(const u16x8*)&qkv[rb + (size_t)i * 1536];
    u16x8 ka = *(const u16x8*)&qkv[rb + (size_t)i * 1536 + 512];
    u16x8 va = *(const u16x8*)&qkv[rb + (size_t)i * 1536 + 1024];
    #pragma unroll
    for (int d = 0; d < 8; ++d) { q[i][d] = b2f(qa[d]); k[i][d] = b2f(ka[d]); v[i][d] = b2f(va[d]); }
  }
  float s[9];
  #pragma unroll
  for (int i = 0; i < 3; ++i)
    #pragma unroll
    for (int j = 0; j < 3; ++j) {
      float a = 0.f;
      #pragma unroll
      for (int d = 0; d < 8; ++d) a += q[i][d] * k[j][d];
      s[i * 3 + j] = a;
    }
  #pragma unroll
  for (int m = 1; m < 8; m <<= 1)
    #pragma unroll
    for (int e = 0; e < 9; ++e) s[e] += __shfl_xor(s[e], m);

  const float g0 = gate[(size_t)(b0 + b) * 3 + 0];
  const float g1 = gate[(size_t)(b0 + b) * 3 + 1];
  const float g2 = gate[(size_t)(b0 + b) * 3 + 2];
  const float gg[3] = {g0, g1, g2};

  float o[8] = {};
  const float sc = 0.125f;  // 1/sqrt(64)
  #pragma unroll
  for (int i = 0; i < 3; ++i) {
    const float a0 = s[i * 3 + 0] * sc, a1 = s[i * 3 + 1] * sc, a2 = s[i * 3 + 2] * sc;
    const float mx = fmaxf(a0, fmaxf(a1, a2));
    float e0 = __expf(a0 - mx), e1 = __expf(a1 - mx), e2 = __expf(a2 - mx);
    const float inv = gg[i] / (e0 + e1 + e2);
    e0 *= inv; e1 *= inv; e2 *= inv;
    #pragma unroll
    for (int d = 0; d < 8; ++d)
      o[d] += e0 * v[0][d] + e1 * v[1][d] + e2 * v[2][d];
  }
  u16x8 ov;
  #pragma unroll
  for (int d = 0; d < 8; ++d) ov[d] = f2b(o[d]);
  *(u16x8*)&ctxg[(size_t)(b0 + b) * 512 + h * 64 + ld * 8] = ov;
}

// ---------------------------------------------------------------------------
// classifier tail: logits = h(256) @ cw2(6,256)^T + cb2.  One wave per b.
// ---------------------------------------------------------------------------
__global__ __launch_bounds__(256) void cls2_k(
    const u16* __restrict__ hh, const float* __restrict__ cw2,
    const float* __restrict__ cb2, float* __restrict__ logits)
{
  const int wave = threadIdx.x >> 6, lane = threadIdx.x & 63;
  const int b = blockIdx.x * 4 + wave;
  float x[4];
  u16x4 xa = *(const u16x4*)&hh[(size_t)b * 256 + lane * 4];
  #pragma unroll
  for (int d = 0; d < 4; ++d) x[d] = b2f(xa[d]);
  float s[6] = {};
  #pragma unroll
  for (int j = 0; j < 6; ++j) {
    const float* w = cw2 + j * 256 + lane * 4;
    #pragma unroll
    for (int d = 0; d < 4; ++d) s[j] += x[d] * w[d];
  }
  #pragma unroll
  for (int m = 1; m < 64; m <<= 1)
    #pragma unroll
    for (int j = 0; j < 6; ++j) s[j] += __shfl_xor(s[j], m);
  if (lane < 6) logits[(size_t)b * 6 + lane] = s[lane] + cb2[lane];
}

// ---------------------------------------------------------------------------
extern "C" void kernel_launch(void* const* d_in, const int* in_sizes, int n_in,
                              void* d_out, int out_size, void* d_ws, size_t ws_size,
                              hipStream_t stream) {
  const float* rgb       = (const float*)d_in[0];
  const float* pose      = (const float*)d_in[1];
  const float* flow      = (const float*)d_in[2];
  const float* rgb_w     = (const float*)d_in[3];
  const float* rgb_b     = (const float*)d_in[4];
  const float* rgb_g     = (const float*)d_in[5];
  const float* rgb_beta  = (const float*)d_in[6];
  const float* pose_w    = (const float*)d_in[7];
  const float* pose_b    = (const float*)d_in[8];
  const float* pose_g    = (const float*)d_in[9];
  const float* pose_beta = (const float*)d_in[10];
  const float* flow_w    = (const float*)d_in[11];
  const float* flow_b    = (const float*)d_in[12];
  const float* flow_g    = (const float*)d_in[13];
  const float* flow_beta = (const float*)d_in[14];
  const float* in_w      = (const float*)d_in[15];
  const float* in_b      = (const float*)d_in[16];
  const float* out_w     = (const float*)d_in[17];
  const float* out_b     = (const float*)d_in[18];
  const float* gw1       = (const float*)d_in[19];
  const float* gb1       = (const float*)d_in[20];
  const float* gw2       = (const float*)d_in[21];
  const float* gb2       = (const float*)d_in[22];
  const float* cw1       = (const float*)d_in[23];
  const float* cb1       = (const float*)d_in[24];
  const float* cg        = (const float*)d_in[25];
  const float* cbeta     = (const float*)d_in[26];
  const float* cw2       = (const float*)d_in[27];
  const float* cb2       = (const float*)d_in[28];

  float* logits_out = (float*)d_out;                      // (16384, 6)
  float* gate_out   = (float*)d_out + (size_t)BATCH * 6;  // (16384, 3)

  // ---- static workspace layout, peak 165,806,080 B -------------------------
  // [0, 6.42M)      : 7 weight matrices, bf16
  // rpfB [6.42M)    : rpf (B,1536) bf16 (live until qkv chunk 2)
  // B2  [56.75M)    : raw (B,1536) -> qkv chunk (24576,1536) overlays
  // C   [132.25M)   : gateh (B,512) -> fusedb overlays after gate2
  // D   [149.03M)   : ctxg (B,512) -> cls_tmp (B,256) + h_bf overlay
  char* ws = (char*)d_ws;
  u16* w_rgb  = (u16*)(ws + 0);
  u16* w_pose = (u16*)(ws + 786432);
  u16* w_flow = (u16*)(ws + 1441792);
  u16* w_in   = (u16*)(ws + 2490368);
  u16* w_out  = (u16*)(ws + 4063232);
  u16* w_g1   = (u16*)(ws + 4587520);
  u16* w_c1   = (u16*)(ws + 6160384);
  char* rpfB = ws + 6422528;
  char* B2   = ws + 56754176;
  char* Cb   = ws + 132251648;
  char* Db   = ws + 149028864;

  u16*   rpf      = (u16*)rpfB;     // (B,1536) bf16 — also the (3B,512) view
  u16*   raw      = (u16*)B2;       // (B,1536) bf16 pre-LN proj outputs
  u16*   qkv_buf  = (u16*)B2;       // (24576,1536) bf16 chunk (raw dead)
  u16*   gateh    = (u16*)Cb;       // (B,512) bf16
  u16*   fusedb   = (u16*)Cb;       // overlay (gateh dead after gate2)
  u16*   ctxg     = (u16*)Db;       // (B,512) bf16 gated context
  u16*   cls_tmp  = (u16*)Db;       // (B,256) bf16 overlay (ctxg dead)
  u16*   h_bf     = (u16*)(Db + 8388608);

  // ---- 1. convert GEMM weights to bf16 (6.4 MB) ----------------------------
  CvtJobs J;
  const float* srcs[7] = {rgb_w, pose_w, flow_w, in_w, out_w, gw1, cw1};
  u16* dsts[7] = {w_rgb, w_pose, w_flow, w_in, w_out, w_g1, w_c1};
  int ns[7] = {512 * 768, 512 * 640, 512 * 1024, 1536 * 512, 512 * 512, 512 * 1536, 256 * 512};
  for (int i = 0; i < 7; ++i) { J.s[i] = srcs[i]; J.d[i] = dsts[i]; J.n4[i] = ns[i] / 4; }
  cvt_w<<<128, 256, 0, stream>>>(J);

  dim3 blk(256);
  // ---- 2. fused 3-proj GEMM (fp32 A direct) -> raw; ln3 -> rpf -------------
  P3 p;
  p.A[0] = rgb;  p.W[0] = w_rgb;  p.bias[0] = rgb_b;  p.K[0] = 768;  p.coff[0] = 0;
  p.A[1] = pose; p.W[1] = w_pose; p.bias[1] = pose_b; p.K[1] = 640;  p.coff[1] = 512;
  p.A[2] = flow; p.W[2] = w_flow; p.bias[2] = flow_b; p.K[2] = 1024; p.coff[2] = 1024;
  p.C = raw;
  proj3_k<<<dim3(4, BATCH / 128, 3), blk, 0, stream>>>(p);
  ln3_k<<<BATCH / 2, dim3(384), 0, stream>>>(raw, rpf, rgb_g, rgb_beta, pose_g, pose_beta, flow_g, flow_beta);

  // ---- 3. gate MLP (needs only rpf): gate1 GEMM + gate2 softmax ------------
  gemm128<2><<<dim3(4, BATCH / 128), blk, 0, stream>>>(rpf, w_g1, gb1, gateh, 1536, 512, 0);
  gate2_k<<<BATCH / 4, blk, 0, stream>>>(gateh, gw2, gb2, gate_out);

  // ---- 4. qkv GEMM + gated attention, 2 chunks of 8192 samples -------------
  for (int c = 0; c < 2; ++c) {
    const u16* a_chunk = rpf + (size_t)c * 8192 * 1536;   // (24576,512) view
    gemm128<1><<<dim3(12, 3 * 8192 / 128), blk, 0, stream>>>(
        a_chunk, w_in, in_b, qkv_buf, 512, 1536, 0);
    attn_gate_k<<<8192 / 4, blk, 0, stream>>>(qkv_buf, gate_out, ctxg, c * 8192);
  }

  // ---- 5. out-proj on the GATED sum (B x 512 -> 512) — 3x less work --------
  gemm128<1><<<dim3(4, BATCH / 128), blk, 0, stream>>>(ctxg, w_out, out_b, fusedb, 512, 512, 0);

  // ---- 6. classifier: GEMM -> LN+ReLU -> logits ----------------------------
  gemm128<1><<<dim3(2, BATCH / 128), blk, 0, stream>>>(fusedb, w_c1, cb1, cls_tmp, 512, 256, 0);
  ln_relu_k<256><<<BATCH / 4, blk, 0, stream>>>(cls_tmp, h_bf, cg, cbeta);
  cls2_k<<<BATCH / 4, blk, 0, stream>>>(h_bf, cw2, cb2, logits_out);

  (void)in_sizes; (void)n_in; (void)out_size; (void)ws_size;
}

// Round 6
// 549.684 us; speedup vs baseline: 1.2815x; 1.0451x over previous
//
#include <hip/hip_runtime.h>

// ---------------------------------------------------------------------------
// AttentionFusion: 3-modality proj(+LN+ReLU) -> 3-token MHA -> gated fusion
// -> classifier.  B=16384, E=512, H=8, HD=64, NC=6.
// R6: XCD-aware block swizzle on all GEMMs — N-blocks sharing an A row-tile
// get linear IDs differing by 8 -> same XCD (round-robin) -> A fetched once
// per XCD's L2 instead of once per N-block.  (R5 profile: proj3 FETCH 314 MB
// = 2x the 159 MB fp32 inputs; fetch-bound at 2.9 TB/s.)
// Everything else identical to R5 (574 us): gate-before-attention algebra,
// fp32-A direct proj, 128x128 bf16 MFMA core, LDS dbuf 1 barrier/step.
// Workspace peak 165,806,080 B.
// ---------------------------------------------------------------------------

typedef unsigned short u16;
typedef __bf16 bf16x8 __attribute__((ext_vector_type(8)));
typedef float f32x4  __attribute__((ext_vector_type(4)));
typedef unsigned short u16x8 __attribute__((ext_vector_type(8)));
typedef unsigned short u16x4 __attribute__((ext_vector_type(4)));

#define BATCH 16384

__device__ __forceinline__ u16 f2b(float f) {   // RNE f32->bf16
  union { float f; unsigned int u; } c; c.f = f;
  unsigned int u = c.u;
  return (u16)((u + 0x7fffu + ((u >> 16) & 1u)) >> 16);
}
__device__ __forceinline__ float b2f(u16 h) {
  union { unsigned int u; float f; } c; c.u = ((unsigned int)h) << 16;
  return c.f;
}

// ---------------------------------------------------------------------------
// fp32 -> bf16 conversion for the 7 GEMM weight matrices (6.4 MB total)
// ---------------------------------------------------------------------------
struct CvtJobs {
  const float* s[7];
  u16* d[7];
  int n4[7];
};

__global__ __launch_bounds__(256) void cvt_w(CvtJobs J) {
  const int stride = gridDim.x * blockDim.x;
  const int tid = blockIdx.x * blockDim.x + threadIdx.x;
  for (int ji = 0; ji < 7; ++ji) {
    const f32x4* __restrict__ s = (const f32x4*)J.s[ji];
    u16x4* __restrict__ d = (u16x4*)J.d[ji];
    const int n4 = J.n4[ji];
    for (int i = tid; i < n4; i += stride) {
      f32x4 v = s[i];
      u16x4 o;
      #pragma unroll
      for (int c = 0; c < 4; ++c) o[c] = f2b(v[c]);
      d[i] = o;
    }
  }
}

// ---------------------------------------------------------------------------
// bf16 GEMM: C(M,N) = A(M,K) @ B(N,K)^T + bias [+ReLU].  128x128 tile, BK=32,
// 4 waves each 64x64 (4x4 of 16x16x32 MFMA).  LDS double-buffered, ONE
// barrier per k-step, prefetch issued right after the barrier.
// 1-D grid of NB * Mblocks (Mblocks % 8 == 0), XCD-swizzled: the NB N-blocks
// of one M-block get IDs differing by 8 -> same XCD under round-robin.
// ---------------------------------------------------------------------------
template<int EPI>   // 1=bias, 2=bias+relu
__global__ __launch_bounds__(256) void gemm128(
    const u16* __restrict__ A, const u16* __restrict__ Bw,
    const float* __restrict__ bias, u16* __restrict__ C,
    int K, int ldc, int coff, int NB)
{
  __shared__ __align__(16) u16 As[2][4096];
  __shared__ __align__(16) u16 Bs[2][4096];
  // XCD swizzle decode
  const int id = blockIdx.x;
  const int rr = id & 7, jj = id >> 3;
  const int nb = jj % NB;
  const int mb = rr + ((jj / NB) << 3);
  const int m0 = mb << 7;
  const int n0 = nb << 7;

  const int t = threadIdx.x;
  const int wave = t >> 6, lane = t & 63;
  const int wm = wave & 1, wn = wave >> 1;
  const int lr  = lane & 15;
  const int lk8 = (lane >> 4) << 3;
  const int srow = t >> 2;
  const int scol = (t & 3) << 4;

  f32x4 acc[4][4] = {};

  const size_t rowB = (size_t)K * 2;
  const char* Ab = (const char*)A + (size_t)m0 * rowB + scol;
  const char* Bb = (const char*)Bw + (size_t)n0 * rowB + scol;

  auto stage = [&](int s, int buf) {
    const char* Ak = Ab + (size_t)s * 64;
    const char* Bk = Bb + (size_t)s * 64;
    #pragma unroll
    for (int j = 0; j < 2; ++j) {
      __builtin_amdgcn_global_load_lds(
          (const __attribute__((address_space(1))) void*)(Ak + (size_t)(j * 64 + srow) * rowB),
          (__attribute__((address_space(3))) void*)((char*)As[buf] + (j << 12) + (wave << 10)),
          16, 0, 0);
      __builtin_amdgcn_global_load_lds(
          (const __attribute__((address_space(1))) void*)(Bk + (size_t)(j * 64 + srow) * rowB),
          (__attribute__((address_space(3))) void*)((char*)Bs[buf] + (j << 12) + (wave << 10)),
          16, 0, 0);
    }
  };

  const int nsteps = K >> 5;
  stage(0, 0);
  for (int s = 0; s < nsteps; ++s) {
    const int cur = s & 1;
    __syncthreads();
    if (s + 1 < nsteps) stage(s + 1, cur ^ 1);

    bf16x8 af[4], bfr[4];
    #pragma unroll
    for (int mi = 0; mi < 4; ++mi) {
      const int r = (wm << 6) + (mi << 4) + lr;
      af[mi] = __builtin_bit_cast(bf16x8, *(const u16x8*)&As[cur][r * 32 + lk8]);
    }
    #pragma unroll
    for (int ni = 0; ni < 4; ++ni) {
      const int r = (wn << 6) + (ni << 4) + lr;
      bfr[ni] = __builtin_bit_cast(bf16x8, *(const u16x8*)&Bs[cur][r * 32 + lk8]);
    }
    #pragma unroll
    for (int mi = 0; mi < 4; ++mi)
      #pragma unroll
      for (int ni = 0; ni < 4; ++ni)
        acc[mi][ni] = __builtin_amdgcn_mfma_f32_16x16x32_bf16(
            af[mi], bfr[ni], acc[mi][ni], 0, 0, 0);
  }

  // C/D layout (m89-verified): col = lane&15, row = (lane>>4)*4 + reg
  const int rquad = (lane >> 4) << 2;
  #pragma unroll
  for (int ni = 0; ni < 4; ++ni) {
    const int col = n0 + (wn << 6) + (ni << 4) + lr;
    const float bv = bias[col];
    #pragma unroll
    for (int mi = 0; mi < 4; ++mi) {
      const int rowb = m0 + (wm << 6) + (mi << 4) + rquad;
      #pragma unroll
      for (int r = 0; r < 4; ++r) {
        float v = acc[mi][ni][r] + bv;
        if (EPI == 2) v = fmaxf(v, 0.0f);
        C[(size_t)(rowb + r) * ldc + coff + col] = f2b(v);
      }
    }
  }
}

// ---------------------------------------------------------------------------
// Fused 3-modality projection GEMM, fp32 A read directly from the inputs.
// A path: per-lane global f32x4 loads -> in-register bf16 cvt -> ds_write
// (LDS holds bf16; MFMA inner loop identical to gemm128). B via
// global_load_lds.  1-D grid of 1536, XCD-swizzled: the 4 N-blocks of one
// (m,z) A-tile get IDs differing by 8 -> same XCD.
// ---------------------------------------------------------------------------
struct P3 {
  const float* A[3];
  const u16* W[3];
  const float* bias[3];
  int K[3];
  int coff[3];
  u16* C;
};

__global__ __launch_bounds__(256) void proj3_k(P3 p) {
  __shared__ __align__(16) u16 As[2][4096];
  __shared__ __align__(16) u16 Bs[2][4096];
  // XCD swizzle decode: id -> (nb in 0..3, mz in 0..383); 4 nb's share XCD
  const int id = blockIdx.x;
  const int rr = id & 7, jj = id >> 3;
  const int nb = jj & 3;
  const int mz = rr + ((jj >> 2) << 3);
  const int mb = mz & 127;
  const int z  = mz >> 7;
  const int m0 = mb << 7;
  const int n0 = nb << 7;

  const float* __restrict__ A = p.A[z];
  const u16* __restrict__ Bw = p.W[z];
  const int K = p.K[z];

  const int t = threadIdx.x;
  const int wave = t >> 6, lane = t & 63;
  const int wm = wave & 1, wn = wave >> 1;
  const int lr  = lane & 15;
  const int lk8 = (lane >> 4) << 3;
  // A reg-staging: round j covers rows j*32+(t>>3); cols (t&7)*4..+3 (fp32)
  const int ar = t >> 3;
  const int ac = (t & 7) << 2;
  // B staging via global_load_lds
  const int srow = t >> 2;
  const int scol = (t & 3) << 4;

  f32x4 acc[4][4] = {};

  const size_t rowA = (size_t)K;        // floats
  const size_t rowB = (size_t)K * 2;    // bytes
  const float* Abase = A + (size_t)m0 * rowA + ac;
  const char* Bb = (const char*)Bw + (size_t)n0 * rowB + scol;

  f32x4 areg[4];
  auto loadA = [&](int s) {
    const float* Ak = Abase + s * 32;
    #pragma unroll
    for (int j = 0; j < 4; ++j)
      areg[j] = *(const f32x4*)(Ak + (size_t)(j * 32 + ar) * rowA);
  };
  auto writeA = [&](int buf) {
    #pragma unroll
    for (int j = 0; j < 4; ++j) {
      u16x4 o;
      #pragma unroll
      for (int c = 0; c < 4; ++c) o[c] = f2b(areg[j][c]);
      *(u16x4*)&As[buf][(j * 32 + ar) * 32 + ac] = o;
    }
  };
  auto stageB = [&](int s, int buf) {
    const char* Bk = Bb + (size_t)s * 64;
    #pragma unroll
    for (int j = 0; j < 2; ++j)
      __builtin_amdgcn_global_load_lds(
          (const __attribute__((address_space(1))) void*)(Bk + (size_t)(j * 64 + srow) * rowB),
          (__attribute__((address_space(3))) void*)((char*)Bs[buf] + (j << 12) + (wave << 10)),
          16, 0, 0);
  };

  const int nsteps = K >> 5;
  loadA(0);
  stageB(0, 0);
  writeA(0);
  for (int s = 0; s < nsteps; ++s) {
    const int cur = s & 1;
    __syncthreads();                       // publishes buf[cur]
    if (s + 1 < nsteps) { loadA(s + 1); stageB(s + 1, cur ^ 1); }

    bf16x8 af[4], bfr[4];
    #pragma unroll
    for (int mi = 0; mi < 4; ++mi) {
      const int r = (wm << 6) + (mi << 4) + lr;
      af[mi] = __builtin_bit_cast(bf16x8, *(const u16x8*)&As[cur][r * 32 + lk8]);
    }
    #pragma unroll
    for (int ni = 0; ni < 4; ++ni) {
      const int r = (wn << 6) + (ni << 4) + lr;
      bfr[ni] = __builtin_bit_cast(bf16x8, *(const u16x8*)&Bs[cur][r * 32 + lk8]);
    }
    #pragma unroll
    for (int mi = 0; mi < 4; ++mi)
      #pragma unroll
      for (int ni = 0; ni < 4; ++ni)
        acc[mi][ni] = __builtin_amdgcn_mfma_f32_16x16x32_bf16(
            af[mi], bfr[ni], acc[mi][ni], 0, 0, 0);

    if (s + 1 < nsteps) writeA(cur ^ 1);   // cvt + LDS write for next step
  }

  const int rquad = (lane >> 4) << 2;
  #pragma unroll
  for (int ni = 0; ni < 4; ++ni) {
    const int col = n0 + (wn << 6) + (ni << 4) + lr;
    const float bv = p.bias[z][col];
    #pragma unroll
    for (int mi = 0; mi < 4; ++mi) {
      const int rowb = m0 + (wm << 6) + (mi << 4) + rquad;
      #pragma unroll
      for (int r = 0; r < 4; ++r) {
        p.C[(size_t)(rowb + r) * 1536 + p.coff[z] + col] = f2b(acc[mi][ni][r] + bv);
      }
    }
  }
}

// ---------------------------------------------------------------------------
// LN+ReLU over all 3 modality slices of raw (B,1536) bf16 -> rpf (B,1536).
// 384 threads = 6 waves = 2 samples x 3 modalities; one wave per 512-slice.
// ---------------------------------------------------------------------------
__global__ __launch_bounds__(384) void ln3_k(
    const u16* __restrict__ raw, u16* __restrict__ dst,
    const float* __restrict__ g0, const float* __restrict__ b0,
    const float* __restrict__ g1, const float* __restrict__ b1,
    const float* __restrict__ g2, const float* __restrict__ b2)
{
  const int wave = threadIdx.x >> 6, lane = threadIdx.x & 63;
  const int m = wave % 3;
  const int b = blockIdx.x * 2 + wave / 3;
  const size_t off = (size_t)b * 1536 + m * 512 + lane * 8;
  u16x8 xa = *(const u16x8*)&raw[off];
  float x[8];
  float sum = 0.f, sq = 0.f;
  #pragma unroll
  for (int d = 0; d < 8; ++d) { float f = b2f(xa[d]); x[d] = f; sum += f; sq += f * f; }
  #pragma unroll
  for (int o = 32; o > 0; o >>= 1) { sum += __shfl_xor(sum, o); sq += __shfl_xor(sq, o); }
  const float mean = sum * (1.0f / 512.0f);
  const float var = sq * (1.0f / 512.0f) - mean * mean;
  const float rs = rsqrtf(var + 1e-5f);
  const float* g = (m == 0) ? g0 : (m == 1) ? g1 : g2;
  const float* bb = (m == 0) ? b0 : (m == 1) ? b1 : b2;
  u16x8 o;
  #pragma unroll
  for (int d = 0; d < 8; ++d) {
    float y = (x[d] - mean) * rs * g[lane * 8 + d] + bb[lane * 8 + d];
    o[d] = f2b(fmaxf(y, 0.0f));
  }
  *(u16x8*)&dst[off] = o;
}

// ---------------------------------------------------------------------------
// Row LayerNorm + ReLU, bf16 in -> bf16 out. One wave per row, 4 rows/block.
// ---------------------------------------------------------------------------
template<int E>
__global__ __launch_bounds__(256) void ln_relu_k(
    const u16* __restrict__ src, u16* __restrict__ dst,
    const float* __restrict__ gg, const float* __restrict__ bb)
{
  constexpr int V = E >> 6;
  const int wave = threadIdx.x >> 6, lane = threadIdx.x & 63;
  const int row = blockIdx.x * 4 + wave;
  const u16* s = src + (size_t)row * E + lane * V;
  float x[V];
  float sum = 0.f, sq = 0.f;
  #pragma unroll
  for (int i = 0; i < V; i += 4) {
    u16x4 v = *(const u16x4*)(s + i);
    #pragma unroll
    for (int c = 0; c < 4; ++c) { float f = b2f(v[c]); x[i + c] = f; sum += f; sq += f * f; }
  }
  #pragma unroll
  for (int off = 32; off > 0; off >>= 1) {
    sum += __shfl_xor(sum, off);
    sq  += __shfl_xor(sq,  off);
  }
  const float invE = 1.0f / (float)E;
  const float m = sum * invE;
  const float var = sq * invE - m * m;
  const float rs = rsqrtf(var + 1e-5f);
  u16* d = dst + (size_t)row * E + lane * V;
  const float* g = gg + lane * V;
  const float* b = bb + lane * V;
  #pragma unroll
  for (int i = 0; i < V; i += 4) {
    u16x4 o;
    #pragma unroll
    for (int c = 0; c < 4; ++c) {
      float y = (x[i + c] - m) * rs * g[i + c] + b[i + c];
      o[c] = f2b(fmaxf(y, 0.0f));
    }
    *(u16x4*)(d + i) = o;
  }
}

// ---------------------------------------------------------------------------
// gate2: (512->3) + softmax.  One wave per sample; writes gate_out (B,3) fp32.
// ---------------------------------------------------------------------------
__global__ __launch_bounds__(256) void gate2_k(
    const u16* __restrict__ gateh, const float* __restrict__ gw2,
    const float* __restrict__ gb2, float* __restrict__ gate_out)
{
  const int wave = threadIdx.x >> 6, lane = threadIdx.x & 63;
  const int b = blockIdx.x * 4 + wave;
  float x[8];
  u16x8 xa = *(const u16x8*)&gateh[(size_t)b * 512 + lane * 8];
  #pragma unroll
  for (int d = 0; d < 8; ++d) x[d] = b2f(xa[d]);
  float s[3] = {0.f, 0.f, 0.f};
  #pragma unroll
  for (int j = 0; j < 3; ++j) {
    const float* w = gw2 + j * 512 + lane * 8;
    #pragma unroll
    for (int d = 0; d < 8; ++d) s[j] += x[d] * w[d];
  }
  #pragma unroll
  for (int m = 1; m < 64; m <<= 1)
    #pragma unroll
    for (int j = 0; j < 3; ++j) s[j] += __shfl_xor(s[j], m);
  if (lane == 0) {
    #pragma unroll
    for (int j = 0; j < 3; ++j) s[j] += gb2[j];
    const float mx = fmaxf(s[0], fmaxf(s[1], s[2]));
    float e0 = __expf(s[0] - mx), e1 = __expf(s[1] - mx), e2 = __expf(s[2] - mx);
    const float inv = 1.0f / (e0 + e1 + e2);
    gate_out[b * 3 + 0] = e0 * inv;
    gate_out[b * 3 + 1] = e1 * inv;
    gate_out[b * 3 + 2] = e2 * inv;
  }
}

// ---------------------------------------------------------------------------
// 3-token 8-head attention + gate application for a chunk of NB samples.
// qkv: (3*NB,1536) bf16 [q|k|v]; emits the GATED context sum directly:
// ctxg[b0+b] = sum_i gate_i * ctx_i   (exact: out-proj is linear, sum g = 1).
// 8 lanes per (b,h), each lane owns 8 of the 64 head dims.
// ---------------------------------------------------------------------------
__global__ __launch_bounds__(256) void attn_gate_k(
    const u16* __restrict__ qkv, const float* __restrict__ gate,
    u16* __restrict__ ctxg, int b0)
{
  const int gid = blockIdx.x * 256 + threadIdx.x;
  const int b = gid >> 6;
  const int h = (threadIdx.x >> 3) & 7;
  const int ld = threadIdx.x & 7;
  const size_t rb = (size_t)(3 * b) * 1536 + h * 64 + ld * 8;

  float q[3][8], k[3][8], v[3][8];
  #pragma unroll
  for (int i = 0; i < 3; ++i) {
    u16x8 qa = *(const u16x8*)&qkv[rb + (size_t)i * 1536];
    u16x8 ka = *(const u16x8*)&qkv[rb + (size_t)i * 1536 + 512];
    u16x8 va = *(const u16x8*)&qkv[rb + (size_t)i * 1536 + 1024];
    #pragma unroll
    for (int d = 0; d < 8; ++d) { q[i][d] = b2f(qa[d]); k[i][d] = b2f(ka[d]); v[i][d] = b2f(va[d]); }
  }
  float s[9];
  #pragma unroll
  for (int i = 0; i < 3; ++i)
    #pragma unroll
    for (int j = 0; j < 3; ++j) {
      float a = 0.f;
      #pragma unroll
      for (int d = 0; d < 8; ++d) a += q[i][d] * k[j][d];
      s[i * 3 + j] = a;
    }
  #pragma unroll
  for (int m = 1; m < 8; m <<= 1)
    #pragma unroll
    for (int e = 0; e < 9; ++e) s[e] += __shfl_xor(s[e], m);

  const float g0 = gate[(size_t)(b0 + b) * 3 + 0];
  const float g1 = gate[(size_t)(b0 + b) * 3 + 1];
  const float g2 = gate[(size_t)(b0 + b) * 3 + 2];
  const float gg[3] = {g0, g1, g2};

  float o[8] = {};
  const float sc = 0.125f;  // 1/sqrt(64)
  #pragma unroll
  for (int i = 0; i < 3; ++i) {
    const float a0 = s[i * 3 + 0] * sc, a1 = s[i * 3 + 1] * sc, a2 = s[i * 3 + 2] * sc;
    const float mx = fmaxf(a0, fmaxf(a1, a2));
    float e0 = __expf(a0 - mx), e1 = __expf(a1 - mx), e2 = __expf(a2 - mx);
    const float inv = gg[i] / (e0 + e1 + e2);
    e0 *= inv; e1 *= inv; e2 *= inv;
    #pragma unroll
    for (int d = 0; d < 8; ++d)
      o[d] += e0 * v[0][d] + e1 * v[1][d] + e2 * v[2][d];
  }
  u16x8 ov;
  #pragma unroll
  for (int d = 0; d < 8; ++d) ov[d] = f2b(o[d]);
  *(u16x8*)&ctxg[(size_t)(b0 + b) * 512 + h * 64 + ld * 8] = ov;
}

// ---------------------------------------------------------------------------
// classifier tail: logits = h(256) @ cw2(6,256)^T + cb2.  One wave per b.
// ---------------------------------------------------------------------------
__global__ __launch_bounds__(256) void cls2_k(
    const u16* __restrict__ hh, const float* __restrict__ cw2,
    const float* __restrict__ cb2, float* __restrict__ logits)
{
  const int wave = threadIdx.x >> 6, lane = threadIdx.x & 63;
  const int b = blockIdx.x * 4 + wave;
  float x[4];
  u16x4 xa = *(const u16x4*)&hh[(size_t)b * 256 + lane * 4];
  #pragma unroll
  for (int d = 0; d < 4; ++d) x[d] = b2f(xa[d]);
  float s[6] = {};
  #pragma unroll
  for (int j = 0; j < 6; ++j) {
    const float* w = cw2 + j * 256 + lane * 4;
    #pragma unroll
    for (int d = 0; d < 4; ++d) s[j] += x[d] * w[d];
  }
  #pragma unroll
  for (int m = 1; m < 64; m <<= 1)
    #pragma unroll
    for (int j = 0; j < 6; ++j) s[j] += __shfl_xor(s[j], m);
  if (lane < 6) logits[(size_t)b * 6 + lane] = s[lane] + cb2[lane];
}

// ---------------------------------------------------------------------------
extern "C" void kernel_launch(void* const* d_in, const int* in_sizes, int n_in,
                              void* d_out, int out_size, void* d_ws, size_t ws_size,
                              hipStream_t stream) {
  const float* rgb       = (const float*)d_in[0];
  const float* pose      = (const float*)d_in[1];
  const float* flow      = (const float*)d_in[2];
  const float* rgb_w     = (const float*)d_in[3];
  const float* rgb_b     = (const float*)d_in[4];
  const float* rgb_g     = (const float*)d_in[5];
  const float* rgb_beta  = (const float*)d_in[6];
  const float* pose_w    = (const float*)d_in[7];
  const float* pose_b    = (const float*)d_in[8];
  const float* pose_g    = (const float*)d_in[9];
  const float* pose_beta = (const float*)d_in[10];
  const float* flow_w    = (const float*)d_in[11];
  const float* flow_b    = (const float*)d_in[12];
  const float* flow_g    = (const float*)d_in[13];
  const float* flow_beta = (const float*)d_in[14];
  const float* in_w      = (const float*)d_in[15];
  const float* in_b      = (const float*)d_in[16];
  const float* out_w     = (const float*)d_in[17];
  const float* out_b     = (const float*)d_in[18];
  const float* gw1       = (const float*)d_in[19];
  const float* gb1       = (const float*)d_in[20];
  const float* gw2       = (const float*)d_in[21];
  const float* gb2       = (const float*)d_in[22];
  const float* cw1       = (const float*)d_in[23];
  const float* cb1       = (const float*)d_in[24];
  const float* cg        = (const float*)d_in[25];
  const float* cbeta     = (const float*)d_in[26];
  const float* cw2       = (const float*)d_in[27];
  const float* cb2       = (const float*)d_in[28];

  float* logits_out = (float*)d_out;                      // (16384, 6)
  float* gate_out   = (float*)d_out + (size_t)BATCH * 6;  // (16384, 3)

  // ---- static workspace layout, peak 165,806,080 B -------------------------
  char* ws = (char*)d_ws;
  u16* w_rgb  = (u16*)(ws + 0);
  u16* w_pose = (u16*)(ws + 786432);
  u16* w_flow = (u16*)(ws + 1441792);
  u16* w_in   = (u16*)(ws + 2490368);
  u16* w_out  = (u16*)(ws + 4063232);
  u16* w_g1   = (u16*)(ws + 4587520);
  u16* w_c1   = (u16*)(ws + 6160384);
  char* rpfB = ws + 6422528;
  char* B2   = ws + 56754176;
  char* Cb   = ws + 132251648;
  char* Db   = ws + 149028864;

  u16*   rpf      = (u16*)rpfB;     // (B,1536) bf16 — also the (3B,512) view
  u16*   raw      = (u16*)B2;       // (B,1536) bf16 pre-LN proj outputs
  u16*   qkv_buf  = (u16*)B2;       // (24576,1536) bf16 chunk (raw dead)
  u16*   gateh    = (u16*)Cb;       // (B,512) bf16
  u16*   fusedb   = (u16*)Cb;       // overlay (gateh dead after gate2)
  u16*   ctxg     = (u16*)Db;       // (B,512) bf16 gated context
  u16*   cls_tmp  = (u16*)Db;       // (B,256) bf16 overlay (ctxg dead)
  u16*   h_bf     = (u16*)(Db + 8388608);

  // ---- 1. convert GEMM weights to bf16 (6.4 MB) ----------------------------
  CvtJobs J;
  const float* srcs[7] = {rgb_w, pose_w, flow_w, in_w, out_w, gw1, cw1};
  u16* dsts[7] = {w_rgb, w_pose, w_flow, w_in, w_out, w_g1, w_c1};
  int ns[7] = {512 * 768, 512 * 640, 512 * 1024, 1536 * 512, 512 * 512, 512 * 1536, 256 * 512};
  for (int i = 0; i < 7; ++i) { J.s[i] = srcs[i]; J.d[i] = dsts[i]; J.n4[i] = ns[i] / 4; }
  cvt_w<<<128, 256, 0, stream>>>(J);

  dim3 blk(256);
  // ---- 2. fused 3-proj GEMM (fp32 A direct, XCD-swizzled) -> raw; ln3 ------
  P3 p;
  p.A[0] = rgb;  p.W[0] = w_rgb;  p.bias[0] = rgb_b;  p.K[0] = 768;  p.coff[0] = 0;
  p.A[1] = pose; p.W[1] = w_pose; p.bias[1] = pose_b; p.K[1] = 640;  p.coff[1] = 512;
  p.A[2] = flow; p.W[2] = w_flow; p.bias[2] = flow_b; p.K[2] = 1024; p.coff[2] = 1024;
  p.C = raw;
  proj3_k<<<1536, blk, 0, stream>>>(p);
  ln3_k<<<BATCH / 2, dim3(384), 0, stream>>>(raw, rpf, rgb_g, rgb_beta, pose_g, pose_beta, flow_g, flow_beta);

  // ---- 3. gate MLP (needs only rpf): gate1 GEMM + gate2 softmax ------------
  gemm128<2><<<4 * (BATCH / 128), blk, 0, stream>>>(rpf, w_g1, gb1, gateh, 1536, 512, 0, 4);
  gate2_k<<<BATCH / 4, blk, 0, stream>>>(gateh, gw2, gb2, gate_out);

  // ---- 4. qkv GEMM + gated attention, 2 chunks of 8192 samples -------------
  for (int c = 0; c < 2; ++c) {
    const u16* a_chunk = rpf + (size_t)c * 8192 * 1536;   // (24576,512) view
    gemm128<1><<<12 * (3 * 8192 / 128), blk, 0, stream>>>(
        a_chunk, w_in, in_b, qkv_buf, 512, 1536, 0, 12);
    attn_gate_k<<<8192 / 4, blk, 0, stream>>>(qkv_buf, gate_out, ctxg, c * 8192);
  }

  // ---- 5. out-proj on the GATED sum (B x 512 -> 512) -----------------------
  gemm128<1><<<4 * (BATCH / 128), blk, 0, stream>>>(ctxg, w_out, out_b, fusedb, 512, 512, 0, 4);

  // ---- 6. classifier: GEMM -> LN+ReLU -> logits ----------------------------
  gemm128<1><<<2 * (BATCH / 128), blk, 0, stream>>>(fusedb, w_c1, cb1, cls_tmp, 512, 256, 0, 2);
  ln_relu_k<256><<<BATCH / 4, blk, 0, stream>>>(cls_tmp, h_bf, cg, cbeta);
  cls2_k<<<BATCH / 4, blk, 0, stream>>>(h_bf, cw2, cb2, logits_out);

  (void)in_sizes; (void)n_in; (void)out_size; (void)ws_size;
}